// Round 7
// baseline (880.648 us; speedup 1.0000x reference)
//
#include <hip/hip_runtime.h>
#include <hip/hip_bf16.h>
#include <hip/hip_fp16.h>

#define F_DIM 128
#define N_RBF 20
#define CUTOFF 5.0f
#define PI_F 3.14159265358979323846f
#define NPB 4   // nodes per k_edge block

typedef float v2f __attribute__((ext_vector_type(2)));
typedef __attribute__((ext_vector_type(8))) short bf16x8;
typedef __attribute__((ext_vector_type(4))) float f32x4;
typedef _Float16 h2f __attribute__((ext_vector_type(2)));
typedef _Float16 f16x8 __attribute__((ext_vector_type(8)));

__device__ __forceinline__ unsigned int bf16_rtne(float f) {
    unsigned int u = __float_as_uint(f);
    u += 0x7fffu + ((u >> 16) & 1u);
    return u >> 16;
}
__device__ __forceinline__ unsigned int pack_bf2(float lo, float hi) {
    return bf16_rtne(lo) | (bf16_rtne(hi) << 16);
}
__device__ __forceinline__ float unpk_lo(unsigned int u) {
    return __uint_as_float(u << 16);
}
__device__ __forceinline__ float unpk_hi(unsigned int u) {
    return __uint_as_float(u & 0xffff0000u);
}
__device__ __forceinline__ float bf16_to_f(unsigned short s) {
    return __uint_as_float(((unsigned int)s) << 16);
}
__device__ __forceinline__ unsigned int pack_h2(float lo, float hi) {
    h2f h = (h2f){(_Float16)lo, (_Float16)hi};
    return __builtin_bit_cast(unsigned int, h);
}
__device__ __forceinline__ unsigned short f16_bits(float f) {
    _Float16 h = (_Float16)f;
    return __builtin_bit_cast(unsigned short, h);
}
__device__ __forceinline__ float f16_to_f(unsigned short s) {
    return (float)__builtin_bit_cast(_Float16, s);
}

// ---------------------------------------------------------------------------
// Merged preprocessing: [0,nbR) rowptr | [nbR,nbR+nbG) geom | rest: weight prep.
__global__ __launch_bounds__(256) void k_pre(
        const int* __restrict__ idx_i, int* __restrict__ row_ptr,
        const float* __restrict__ r, unsigned int* __restrict__ geom,
        const float* __restrict__ muxW,
        const float* __restrict__ W1,
        const float* __restrict__ W2,
        const float* __restrict__ iW1,
        const float* __restrict__ iW2,
        const float* __restrict__ filt_W,
        const float* __restrict__ filt_b,
        unsigned short* __restrict__ muxWt,
        unsigned short* __restrict__ W1t,
        unsigned short* __restrict__ W2t,
        unsigned short* __restrict__ iW1t,
        unsigned short* __restrict__ iW2t,
        unsigned short* __restrict__ filtWt,
        int N, int E, int nbR, int nbG) {
    int bid = blockIdx.x;
    if (bid < nbR) {
        // ---- row_ptr via binary search ----
        int i = bid * 256 + threadIdx.x;
        if (i > N) return;
        if (i == N) { row_ptr[N] = E; return; }
        int lo = 0, hi = E;
        while (lo < hi) {
            int mid = (lo + hi) >> 1;
            if (idx_i[mid] < i) lo = mid + 1; else hi = mid;
        }
        row_ptr[i] = lo;
        return;
    }
    if (bid < nbR + nbG) {
        // ---- geometry record: 16 dwords/edge ----
        int e = (bid - nbR) * 256 + threadIdx.x;
        if (e >= E) return;
        float x = r[e * 3], y = r[e * 3 + 1], z = r[e * 3 + 2];
        float d = sqrtf(x * x + y * y + z * z);
        float inv = 1.f / d;
        float fc = (d < CUTOFF) ? 0.5f * (__cosf(d * (PI_F / CUTOFF)) + 1.f) : 0.f;
        unsigned int* g = geom + (size_t)e * 16;
        float dx = x * inv, dy = y * inv, dz = z * inv;
        g[0] = __float_as_uint(dx);
        g[1] = __float_as_uint(dy);
        g[2] = __float_as_uint(dz);
        g[3] = __float_as_uint(fc);
        const float delta = CUTOFF / (N_RBF - 1);
        const float coeff = -0.5f / (delta * delta);
        float ph[N_RBF];
#pragma unroll
        for (int k = 0; k < N_RBF; k++) {
            float t = d - k * delta;
            ph[k] = __expf(coeff * t * t) * fc;
        }
#pragma unroll
        for (int k = 0; k < N_RBF / 2; k++)
            g[4 + k] = pack_h2(ph[2 * k], ph[2 * k + 1]);
        g[14] = pack_h2(fc, dx);
        g[15] = pack_h2(dy, dz);
        return;
    }
    // ---- weight prep ----
    int idx = (bid - nbR - nbG) * 256 + threadIdx.x;
    if (idx < 98304) {                     // muxWt[l][c<256][k<128]
        int l = idx / 32768, rem = idx % 32768;
        int c = rem / 128, k = rem % 128;
        muxWt[idx] = (unsigned short)bf16_rtne(muxW[l * 32768 + k * 256 + c]);
    } else if (idx < 196608) {             // W1t[l][c<128][k<256]
        int i2 = idx - 98304;
        int l = i2 / 32768, rem = i2 % 32768;
        int c = rem / 256, k = rem % 256;
        W1t[i2] = (unsigned short)bf16_rtne(W1[l * 32768 + k * 128 + c]);
    } else if (idx < 344064) {             // W2t[l][c<384][k<128]
        int i2 = idx - 196608;
        int l = i2 / 49152, rem = i2 % 49152;
        int c = rem / 128, k = rem % 128;
        W2t[i2] = (unsigned short)bf16_rtne(W2[l * 49152 + k * 384 + c]);
    } else if (idx < 393216) {             // iW1t[l][c<128][k<128]
        int i2 = idx - 344064;
        int l = i2 / 16384, rem = i2 % 16384;
        int c = rem / 128, k = rem % 128;
        iW1t[i2] = (unsigned short)bf16_rtne(iW1[l * 16384 + k * 128 + c]);
    } else if (idx < 540672) {             // iW2t[l][c<384][k<128]
        int i2 = idx - 393216;
        int l = i2 / 49152, rem = i2 % 49152;
        int c = rem / 128, k = rem % 128;
        iW2t[i2] = (unsigned short)bf16_rtne(iW2[l * 49152 + k * 384 + c]);
    } else if (idx < 568320) {             // filtWt[l][c<384][k<24] f16
        int i2 = idx - 540672;
        int l = i2 / 9216, rem = i2 % 9216;
        int c = rem / 24, k = rem % 24;
        float v = 0.f;
        if (k < 20)       v = filt_W[k * 1152 + l * 384 + c];
        else if (k == 20) v = filt_b[l * 384 + c];
        _Float16 hv = (_Float16)v;
        filtWt[i2] = __builtin_bit_cast(unsigned short, hv);
    }
}

// ---------------------------------------------------------------------------
// Node message MLP via MFMA (layer 0 only), with q-init fused.
__global__ __launch_bounds__(256) void k_node_mfma(
        const int* __restrict__ Z,
        const float* __restrict__ emb,
        float* __restrict__ q,
        const unsigned short* __restrict__ iW1t,   // [128][128] bf16 (c,k)
        const float* __restrict__ b1,
        const unsigned short* __restrict__ iW2t,   // [384][128]
        const float* __restrict__ b2,
        unsigned int* __restrict__ P, int N) {
    __shared__ unsigned short A[16 * 136];
    __shared__ unsigned short Ah[16 * 136];
    __shared__ float Xs[16 * 396];
    int t = threadIdx.x;
    int w = t >> 6, l = t & 63, quad = l >> 4, c0 = l & 15;
    int n0 = blockIdx.x * 16;

#pragma unroll
    for (int i = 0; i < 4; i++) {
        int flat = i * 256 + t;
        int node = flat >> 6, cp = flat & 63;
        int gn = n0 + node;
        unsigned int v = 0u;
        if (gn < N) {
            const float* s = emb + (size_t)Z[gn] * 128 + 2 * cp;
            float s0 = s[0], s1 = s[1];
            v = pack_bf2(s0, s1);
            float* qo = q + (size_t)gn * 128 + 2 * cp;
            qo[0] = s0; qo[1] = s1;
        }
        *(unsigned int*)&A[node * 136 + 2 * cp] = v;
    }
    __syncthreads();

    bf16x8 a1[4];
#pragma unroll
    for (int ks = 0; ks < 4; ks++)
        a1[ks] = *(const bf16x8*)&A[c0 * 136 + ks * 32 + quad * 8];
#pragma unroll
    for (int jj = 0; jj < 2; jj++) {
        int jg = 2 * w + jj;
        float bb = b1[16 * jg + c0];
        f32x4 acc = (f32x4){bb, bb, bb, bb};
#pragma unroll
        for (int ks = 0; ks < 4; ks++) {
            bf16x8 b = *(const bf16x8*)&iW1t[(16 * jg + c0) * 128 + ks * 32 + quad * 8];
            acc = __builtin_amdgcn_mfma_f32_16x16x32_bf16(a1[ks], b, acc, 0, 0, 0);
        }
#pragma unroll
        for (int r = 0; r < 4; r++) {
            float aa = acc[r];
            Ah[(quad * 4 + r) * 136 + 16 * jg + c0] =
                (unsigned short)bf16_rtne(aa / (1.f + __expf(-aa)));
        }
    }
    __syncthreads();

    bf16x8 a3[4];
#pragma unroll
    for (int ks = 0; ks < 4; ks++)
        a3[ks] = *(const bf16x8*)&Ah[c0 * 136 + ks * 32 + quad * 8];
#pragma unroll
    for (int jj = 0; jj < 6; jj++) {
        int jx = 6 * w + jj;
        float bb = b2[16 * jx + c0];
        f32x4 acc = (f32x4){bb, bb, bb, bb};
#pragma unroll
        for (int ks = 0; ks < 4; ks++) {
            bf16x8 b = *(const bf16x8*)&iW2t[(16 * jx + c0) * 128 + ks * 32 + quad * 8];
            acc = __builtin_amdgcn_mfma_f32_16x16x32_bf16(a3[ks], b, acc, 0, 0, 0);
        }
#pragma unroll
        for (int r = 0; r < 4; r++)
            Xs[(quad * 4 + r) * 396 + 16 * jx + c0] = acc[r];
    }
    __syncthreads();

    int n = t >> 4, fi = (t & 15) * 8;
    int gn = n0 + n;
    if (gn < N) {
        size_t base = (size_t)gn * 384;
        unsigned int d[8];
#pragma unroll
        for (int k = 0; k < 8; k++) {
            float x0 = Xs[n * 396 + fi + k];
            float x1 = Xs[n * 396 + 128 + fi + k];
            float x2 = Xs[n * 396 + 256 + fi + k];
            d[k] = pack_bf2(x0, x1);
            ((unsigned short*)&P[base + 256 + fi + k])[0] = (unsigned short)bf16_rtne(x2);
        }
        *(uint4*)&P[base + fi]     = make_uint4(d[0], d[1], d[2], d[3]);
        *(uint4*)&P[base + fi + 4] = make_uint4(d[4], d[5], d[6], d[7]);
    }
}

// ---------------------------------------------------------------------------
// A-frag loader for the filter MFMA: 24 f16 channels at geom dwords 4..15,
// K padded to 32 (quad 3 = zeros).
__device__ __forceinline__ f16x8 load_phi_frag(const unsigned int* __restrict__ geom,
                                               int ts, int c0, int quad, int E) {
    int ea = ts + c0;
    if (ea >= E) ea = E - 1;          // clamp; pad rows are never aggregated
    f16x8 a = {};
    if (quad < 3)
        a = *(const f16x8*)&geom[(size_t)ea * 16 + 4 + quad * 4];
    return a;
}

// ---------------------------------------------------------------------------
// Edge aggregation, MLP-pipelined one full 16-edge tile ahead.
// The R3-R6 structure held ONE gather group in flight per wave (the
// idx_j -> readfirstlane -> 3-load chain serializes); request-accounting
// shows that starves the memory system (~13 KB in flight vs ~15 KB needed
// per CU). Fix: (a) all 8 j's of a tile fetched with ONE vector load +
// readlane (no idx load in the chain), (b) the whole next tile's 24
// payload dwords issued right after the current tile's consume -> in
// flight across barrier + MFMA + next consume start (8x MLP). Pipeline
// crosses node boundaries (edge rows are contiguous). R2's version of
// this died of VGPR/occupancy (96 VGPR, 27KB LDS, NPB=2); here the lean
// f16-Ws structure keeps LDS at 15.4 KB and launch_bounds(256,6) caps
// registers.
template <bool HAS_MU>
__global__ __launch_bounds__(256, 6) void k_edge(
        const unsigned int* __restrict__ P,
        const unsigned int* __restrict__ geom,
        const int* __restrict__ idx_j,
        const int* __restrict__ row_ptr,
        const unsigned short* __restrict__ filtWt,  // [384][24] f16 (layer slice)
        float* __restrict__ q,
        float* __restrict__ muD, int N, int E) {
    constexpr int NT = HAS_MU ? 6 : 4;     // 16-col tiles per wave (24 or 16 total)
    constexpr int WS = HAS_MU ? 412 : 268; // ushort row stride
    __shared__ unsigned short Ws[16 * WS];
    __shared__ float red[4][128];
    int t = threadIdx.x;
    int f = t & 127;
    int sub = __builtin_amdgcn_readfirstlane(t >> 7);
    int w = t >> 6, l = t & 63, quad = l >> 4, c0 = l & 15;
    int ll8 = l & 7;

    f16x8 Bf[NT];
#pragma unroll
    for (int jj = 0; jj < NT; jj++) {
        int jx = NT * w + jj;
        f16x8 b = {};
        if (quad < 3)
            b = *(const f16x8*)&filtWt[(16 * jx + c0) * 24 + quad * 8];
        Bf[jj] = b;
    }

    int i0 = blockIdx.x * NPB;
    int Rs = __builtin_amdgcn_readfirstlane(row_ptr[i0]);

    // ---- initial pipeline fill: phi frag + 8 j's + 24 payload dwords ----
    unsigned int PA[8], PB[8], PC[8];
    f16x8 aF = load_phi_frag(geom, Rs, c0, quad, E);
    {
        int ea0 = Rs + 2 * ll8 + sub; if (ea0 > E - 1) ea0 = E - 1;
        int idxv = idx_j[ea0];
#pragma unroll
        for (int k = 0; k < 8; k++) {
            int j = __builtin_amdgcn_readlane(idxv, k);
            const unsigned int* Pj = P + (size_t)j * 384;
            PA[k] = Pj[f];
            if (HAS_MU) { PB[k] = Pj[128 + f]; PC[k] = Pj[256 + f]; }
        }
    }

    for (int nn = 0; nn < NPB; nn++) {
        int i = i0 + nn;
        if (i >= N) break;
        int rs = __builtin_amdgcn_readfirstlane(row_ptr[i]);
        int re = __builtin_amdgcn_readfirstlane(row_ptr[i + 1]);
        float dq = 0.f, dm0 = 0.f, dm1 = 0.f, dm2 = 0.f;

        for (int ts = rs; ts < re; ts += 16) {
            // --- filter MFMA: 16 edges -> Ws (f16) ---
#pragma unroll
            for (int jj = 0; jj < NT; jj++) {
                int jx = NT * w + jj;
                f32x4 acc = (f32x4){0.f, 0.f, 0.f, 0.f};
                acc = __builtin_amdgcn_mfma_f32_16x16x32_f16(aF, Bf[jj], acc, 0, 0, 0);
#pragma unroll
                for (int r = 0; r < 4; r++)
                    Ws[(quad * 4 + r) * WS + 16 * jx + c0] = f16_bits(acc[r]);
            }
            // --- prefetch next tile's phi frag + j-vector (crosses nodes) ---
            int nts = (ts + 16 < re) ? ts + 16 : re;
            f16x8 aN = load_phi_frag(geom, nts, c0, quad, E);
            int eaN = nts + 2 * ll8 + sub; if (eaN > E - 1) eaN = E - 1;
            int idxvN = idx_j[eaN];
            __syncthreads();

            // --- consume this tile from registers + Ws ---
            int nv = re - ts; if (nv > 16) nv = 16;
#pragma unroll
            for (int k = 0; k < 8; k++) {
                int eloc = 2 * k + sub;
                float msk = (eloc < nv) ? 1.f : 0.f;
                int ee = ts + eloc; if (ee > E - 1) ee = E - 1;
                const float* g = (const float*)(geom + (size_t)ee * 16);
                float dirx = g[0], diry = g[1], dirz = g[2];

                float wq = f16_to_f(Ws[eloc * WS + f]) * msk;
                float wr = f16_to_f(Ws[eloc * WS + 128 + f]) * msk;

                unsigned int A = PA[k];
                float xq = unpk_lo(A), xr = unpk_hi(A);
                dq += wq * xq;
                float s_r = wr * xr;
                if (HAS_MU) {
                    float wm = f16_to_f(Ws[eloc * WS + 256 + f]) * msk;
                    unsigned int B = PB[k], C = PC[k];
                    float s_m = wm * unpk_lo(C);
                    dm0 += s_r * dirx + s_m * unpk_lo(B);
                    dm1 += s_r * diry + s_m * unpk_hi(B);
                    dm2 += s_r * dirz + s_m * unpk_hi(C);
                } else {
                    dm0 += s_r * dirx;
                    dm1 += s_r * diry;
                    dm2 += s_r * dirz;
                }
            }
            // --- issue next tile's gathers (fly across barrier + MFMA) ---
#pragma unroll
            for (int k = 0; k < 8; k++) {
                int j = __builtin_amdgcn_readlane(idxvN, k);
                const unsigned int* Pj = P + (size_t)j * 384;
                PA[k] = Pj[f];
                if (HAS_MU) { PB[k] = Pj[128 + f]; PC[k] = Pj[256 + f]; }
            }
            aF = aN;
            __syncthreads();
        }

        if (sub == 1) { red[0][f] = dq; red[1][f] = dm0; red[2][f] = dm1; red[3][f] = dm2; }
        __syncthreads();
        if (sub == 0) {
            dq  += red[0][f];
            float d0 = dm0 + red[1][f], d1 = dm1 + red[2][f];
            float d2 = dm2 + red[3][f];
            q[(size_t)i * 128 + f] += dq;
            size_t base = (size_t)i * 384;
            if (HAS_MU) {
                muD[base + f]       += d0;
                muD[base + 128 + f] += d1;
                muD[base + 256 + f] += d2;
            } else {   // layer 0: mu starts at zero
                muD[base + f]       = d0;
                muD[base + 128 + f] = d1;
                muD[base + 256 + f] = d2;
            }
        }
        __syncthreads();
    }
}

// ---------------------------------------------------------------------------
// Fused mixing(l) + node-message(l+1). One-shot mu_mix (48 MFMAs, 8 barriers),
// 54144 B LDS -> 3 blocks/CU.
__global__ __launch_bounds__(256, 3) void k_mix_fused(
        float* __restrict__ q, float* __restrict__ mu,
        const unsigned short* __restrict__ muxWt,   // [256][128] bf16 (c,k)
        const unsigned short* __restrict__ W1t,     // [128][256]
        const unsigned short* __restrict__ W2t,     // [384][128]
        const float* __restrict__ b1,
        const float* __restrict__ b2,
        const unsigned short* __restrict__ niW1t,   // next-layer node W1t
        const float* __restrict__ nib1,
        const unsigned short* __restrict__ niW2t,   // next-layer node W2t
        const float* __restrict__ nib2,
        int has_node,
        unsigned int* __restrict__ P, int N) {
    constexpr int XS = 516;                         // f32 row stride; S at +388
    __shared__ __align__(16) unsigned char LDSm[54144];
    unsigned short* A   = (unsigned short*)LDSm;             // [16][264] bf16
    unsigned short* Wsp = (unsigned short*)(LDSm + 8448);    // [3][16][132] bf16
    float*          Xs  = (float*)(LDSm + 21120);            // [16][516] f32
    unsigned short* Amu = (unsigned short*)(LDSm + 21120);   // [48][136] (aliases Xs)

    int t = threadIdx.x;
    int w = t >> 6, l = t & 63, quad = l >> 4, c0 = l & 15;
    int n0 = blockIdx.x * 16;

    // ---- single staging phase: q -> A[:, 0..128), mu -> Amu[48][128] ----
#pragma unroll
    for (int i = 0; i < 4; i++) {
        int flat = i * 256 + t;
        int node = flat >> 6, cp = flat & 63, gn = n0 + node;
        unsigned int v = 0u;
        if (gn < N) { const float* s = q + (size_t)gn * 128 + 2 * cp; v = pack_bf2(s[0], s[1]); }
        *(unsigned int*)&A[node * 264 + 2 * cp] = v;
    }
#pragma unroll
    for (int i = 0; i < 12; i++) {
        int flat = i * 256 + t;
        int row = flat >> 6, cp = flat & 63;
        int node = row & 15, c = row >> 4, gn = n0 + node;
        unsigned int v = 0u;
        if (gn < N) {
            const float* s = mu + (size_t)gn * 384 + c * 128 + 2 * cp;
            v = pack_bf2(s[0], s[1]);
        }
        *(unsigned int*)&Amu[row * 136 + 2 * cp] = v;
    }
    __syncthreads();                                              // B1

    // ---- one-shot mu_mix: 48 MFMAs, vn2/S in regs, Wm -> Wsp ----
    f32x4 vn2[2], S[2];
#pragma unroll
    for (int jj = 0; jj < 2; jj++) { vn2[jj] = (f32x4){0,0,0,0}; S[jj] = (f32x4){0,0,0,0}; }
#pragma unroll
    for (int rt = 0; rt < 3; rt++) {
        bf16x8 af[4];
#pragma unroll
        for (int ks = 0; ks < 4; ks++)
            af[ks] = *(const bf16x8*)&Amu[(rt * 16 + c0) * 136 + ks * 32 + quad * 8];
#pragma unroll
        for (int jj = 0; jj < 2; jj++) {
            int jv = 2 * w + jj;
            f32x4 V = (f32x4){0,0,0,0}, Wm = (f32x4){0,0,0,0};
#pragma unroll
            for (int ks = 0; ks < 4; ks++) {
                bf16x8 bV = *(const bf16x8*)&muxWt[(16 * jv + c0) * 128 + ks * 32 + quad * 8];
                V = __builtin_amdgcn_mfma_f32_16x16x32_bf16(af[ks], bV, V, 0, 0, 0);
            }
#pragma unroll
            for (int ks = 0; ks < 4; ks++) {
                bf16x8 bW = *(const bf16x8*)&muxWt[(16 * (jv + 8) + c0) * 128 + ks * 32 + quad * 8];
                Wm = __builtin_amdgcn_mfma_f32_16x16x32_bf16(af[ks], bW, Wm, 0, 0, 0);
            }
            vn2[jj] += V * V;
            S[jj]   += V * Wm;
#pragma unroll
            for (int r = 0; r < 4; r++)
                Wsp[rt * 2112 + (quad * 4 + r) * 132 + 16 * jv + c0] =
                    (unsigned short)bf16_rtne(Wm[r]);
        }
    }
    // mu_Vn -> A[:, 128..256) (ctx second half)
#pragma unroll
    for (int jj = 0; jj < 2; jj++) {
        int jv = 2 * w + jj;
#pragma unroll
        for (int r = 0; r < 4; r++)
            A[(quad * 4 + r) * 264 + 128 + 16 * jv + c0] =
                (unsigned short)bf16_rtne(sqrtf(vn2[jj][r] + 1e-8f));
    }
    __syncthreads();                                              // B2

    bf16x8 a2[8];
#pragma unroll
    for (int ks = 0; ks < 8; ks++)
        a2[ks] = *(const bf16x8*)&A[c0 * 264 + ks * 32 + quad * 8];
    {
        unsigned short htmp[2][4];
#pragma unroll
        for (int jj = 0; jj < 2; jj++) {
            int jg = 2 * w + jj;
            float bb = b1[16 * jg + c0];
            f32x4 acc = (f32x4){bb, bb, bb, bb};
#pragma unroll
            for (int ks = 0; ks < 8; ks++) {
                bf16x8 b = *(const bf16x8*)&W1t[(16 * jg + c0) * 256 + ks * 32 + quad * 8];
                acc = __builtin_amdgcn_mfma_f32_16x16x32_bf16(a2[ks], b, acc, 0, 0, 0);
            }
#pragma unroll
            for (int r = 0; r < 4; r++) {
                float aa = acc[r];
                htmp[jj][r] = (unsigned short)bf16_rtne(aa / (1.f + __expf(-aa)));
            }
        }
        __syncthreads();                                          // B3 (WAR vs a2)
#pragma unroll
        for (int jj = 0; jj < 2; jj++) {
            int jg = 2 * w + jj;
#pragma unroll
            for (int r = 0; r < 4; r++)
                A[(quad * 4 + r) * 264 + 128 + 16 * jg + c0] = htmp[jj][r];
        }
    }
    __syncthreads();                                              // B4

    bf16x8 a3[4];
#pragma unroll
    for (int ks = 0; ks < 4; ks++)
        a3[ks] = *(const bf16x8*)&A[c0 * 264 + 128 + ks * 32 + quad * 8];
#pragma unroll
    for (int jj = 0; jj < 6; jj++) {
        int jx = 6 * w + jj;
        float bb = b2[16 * jx + c0];
        f32x4 acc = (f32x4){bb, bb, bb, bb};
#pragma unroll
        for (int ks = 0; ks < 4; ks++) {
            bf16x8 b = *(const bf16x8*)&W2t[(16 * jx + c0) * 128 + ks * 32 + quad * 8];
            acc = __builtin_amdgcn_mfma_f32_16x16x32_bf16(a3[ks], b, acc, 0, 0, 0);
        }
#pragma unroll
        for (int r = 0; r < 4; r++)
            Xs[(quad * 4 + r) * XS + 16 * jx + c0] = acc[r];
    }
#pragma unroll
    for (int jj = 0; jj < 2; jj++) {
        int jv = 2 * w + jj;
#pragma unroll
        for (int r = 0; r < 4; r++)
            Xs[(quad * 4 + r) * XS + 388 + 16 * jv + c0] = S[jj][r];
    }
    __syncthreads();                                              // B5

    int n = t >> 4, fi = (t & 15) * 8;
    int gn = n0 + n;
    if (gn < N) {
        float* qp = q + (size_t)gn * 128 + fi;
        float qn[8];
#pragma unroll
        for (int k = 0; k < 8; k++) {
            qn[k] = qp[k] + Xs[n * XS + fi + k] +
                    Xs[n * XS + 256 + fi + k] * Xs[n * XS + 388 + fi + k];
            qp[k] = qn[k];
        }
        unsigned int qd[4];
#pragma unroll
        for (int p = 0; p < 4; p++) qd[p] = pack_bf2(qn[2 * p], qn[2 * p + 1]);
        *(uint4*)&A[n * 264 + fi] = make_uint4(qd[0], qd[1], qd[2], qd[3]);

        size_t base = (size_t)gn * 384;
        float m[3][8];
#pragma unroll
        for (int c = 0; c < 3; c++) {
            float* mp = mu + base + c * 128 + fi;
#pragma unroll
            for (int k = 0; k < 8; k++) {
                m[c][k] = mp[k] + Xs[n * XS + 128 + fi + k] *
                                  bf16_to_f(Wsp[c * 2112 + n * 132 + fi + k]);
                mp[k] = m[c][k];
            }
        }
        if (has_node) {   // P mu-rows only consumed by the next edge layer
            unsigned int d[8];
#pragma unroll
            for (int k = 0; k < 8; k++) {
                d[k] = pack_bf2(m[0][k], m[1][k]);
                ((unsigned short*)&P[base + 256 + fi + k])[1] = (unsigned short)bf16_rtne(m[2][k]);
            }
            *(uint4*)&P[base + 128 + fi]     = make_uint4(d[0], d[1], d[2], d[3]);
            *(uint4*)&P[base + 128 + fi + 4] = make_uint4(d[4], d[5], d[6], d[7]);
        }
    }
    __syncthreads();                                              // B6

    if (has_node) {
        unsigned short* Ah = Wsp;   // reuse (Wsp reads finished at B6)
        bf16x8 a1[4];
#pragma unroll
        for (int ks = 0; ks < 4; ks++)
            a1[ks] = *(const bf16x8*)&A[c0 * 264 + ks * 32 + quad * 8];
#pragma unroll
        for (int jj = 0; jj < 2; jj++) {
            int jg = 2 * w + jj;
            float bb = nib1[16 * jg + c0];
            f32x4 acc = (f32x4){bb, bb, bb, bb};
#pragma unroll
            for (int ks = 0; ks < 4; ks++) {
                bf16x8 b = *(const bf16x8*)&niW1t[(16 * jg + c0) * 128 + ks * 32 + quad * 8];
                acc = __builtin_amdgcn_mfma_f32_16x16x32_bf16(a1[ks], b, acc, 0, 0, 0);
            }
#pragma unroll
            for (int r = 0; r < 4; r++) {
                float aa = acc[r];
                Ah[(quad * 4 + r) * 136 + 16 * jg + c0] =
                    (unsigned short)bf16_rtne(aa / (1.f + __expf(-aa)));
            }
        }
        __syncthreads();                                          // B7

        bf16x8 a4[4];
#pragma unroll
        for (int ks = 0; ks < 4; ks++)
            a4[ks] = *(const bf16x8*)&Ah[c0 * 136 + ks * 32 + quad * 8];
#pragma unroll
        for (int jj = 0; jj < 6; jj++) {
            int jx = 6 * w + jj;
            float bb = nib2[16 * jx + c0];
            f32x4 acc = (f32x4){bb, bb, bb, bb};
#pragma unroll
            for (int ks = 0; ks < 4; ks++) {
                bf16x8 b = *(const bf16x8*)&niW2t[(16 * jx + c0) * 128 + ks * 32 + quad * 8];
                acc = __builtin_amdgcn_mfma_f32_16x16x32_bf16(a4[ks], b, acc, 0, 0, 0);
            }
#pragma unroll
            for (int r = 0; r < 4; r++)
                Xs[(quad * 4 + r) * XS + 16 * jx + c0] = acc[r];
        }
        __syncthreads();                                          // B8

        if (gn < N) {
            size_t base = (size_t)gn * 384;
            unsigned int d[8];
#pragma unroll
            for (int k = 0; k < 8; k++) {
                float x0 = Xs[n * XS + fi + k];
                float x1 = Xs[n * XS + 128 + fi + k];
                float x2 = Xs[n * XS + 256 + fi + k];
                d[k] = pack_bf2(x0, x1);
                ((unsigned short*)&P[base + 256 + fi + k])[0] = (unsigned short)bf16_rtne(x2);
            }
            *(uint4*)&P[base + fi]     = make_uint4(d[0], d[1], d[2], d[3]);
            *(uint4*)&P[base + fi + 4] = make_uint4(d[4], d[5], d[6], d[7]);
        }
    }
}

// ---------------------------------------------------------------------------
extern "C" void kernel_launch(void* const* d_in, const int* in_sizes, int n_in,
                              void* d_out, int out_size, void* d_ws, size_t ws_size,
                              hipStream_t stream) {
    const int*   Z      = (const int*)d_in[0];
    const float* r_ij   = (const float*)d_in[1];
    const int*   idx_i  = (const int*)d_in[2];
    const int*   idx_j  = (const int*)d_in[3];
    const float* emb    = (const float*)d_in[4];
    const float* filt_W = (const float*)d_in[5];
    const float* filt_b = (const float*)d_in[6];
    const float* int_W1 = (const float*)d_in[7];
    const float* int_b1 = (const float*)d_in[8];
    const float* int_W2 = (const float*)d_in[9];
    const float* int_b2 = (const float*)d_in[10];
    const float* mix_W1 = (const float*)d_in[11];
    const float* mix_b1 = (const float*)d_in[12];
    const float* mix_W2 = (const float*)d_in[13];
    const float* mix_b2 = (const float*)d_in[14];
    const float* mux_W  = (const float*)d_in[15];

    int N = in_sizes[0];
    int E = in_sizes[2];

    float* q   = (float*)d_out;              // [N,128]  q state (fp32)
    float* muD = q + (size_t)N * 128;        // [N,3,128] mu state (fp32)

    unsigned int* geom = (unsigned int*)d_ws;                 // E*16 u32 (64 B/edge)
    unsigned int* P = geom + (size_t)E * 16;                  // N*384 u32
    int* row_ptr = (int*)(P + (size_t)N * 384);               // N+1
    uintptr_t waddr = (uintptr_t)(row_ptr + N + 1);
    waddr = (waddr + 15) & ~(uintptr_t)15;
    unsigned short* muxWt = (unsigned short*)waddr;   // 3*256*128
    unsigned short* W1t   = muxWt + 98304;            // 3*128*256
    unsigned short* W2t   = W1t + 98304;              // 3*384*128
    unsigned short* iW1t  = W2t + 147456;             // 3*128*128
    unsigned short* iW2t  = iW1t + 49152;             // 3*384*128
    unsigned short* filtWt = iW2t + 147456;           // 3*384*24 f16

    int nbR = (N + 1 + 255) / 256;
    int nbG = (E + 255) / 256;
    k_pre<<<nbR + nbG + 2220, 256, 0, stream>>>(
        idx_i, row_ptr, r_ij, geom,
        mux_W, mix_W1, mix_W2, int_W1, int_W2, filt_W, filt_b,
        muxWt, W1t, W2t, iW1t, iW2t, filtWt, N, E, nbR, nbG);

    int tiles = (N + 15) / 16;
    k_node_mfma<<<tiles, 256, 0, stream>>>(
        Z, emb, q, iW1t, int_b1, iW2t, int_b2, P, N);
    for (int l = 0; l < 3; l++) {
        if (l == 0)
            k_edge<false><<<(N + NPB - 1) / NPB, 256, 0, stream>>>(
                P, geom, idx_j, row_ptr, filtWt, q, muD, N, E);
        else
            k_edge<true><<<(N + NPB - 1) / NPB, 256, 0, stream>>>(
                P, geom, idx_j, row_ptr, filtWt + (size_t)l * 9216, q, muD, N, E);
        int nl = (l < 2) ? (l + 1) : 0;
        k_mix_fused<<<tiles, 256, 0, stream>>>(
            q, muD, muxWt + (size_t)l * 32768, W1t + (size_t)l * 32768,
            W2t + (size_t)l * 49152, mix_b1 + l * 128, mix_b2 + l * 384,
            iW1t + (size_t)nl * 16384, int_b1 + nl * 128,
            iW2t + (size_t)nl * 49152, int_b2 + nl * 384,
            (l < 2) ? 1 : 0, P, N);
    }
    // q in d_out; final mu (fp32 state) in muD = d_out mu region.
}

// Round 8
// 532.980 us; speedup vs baseline: 1.6523x; 1.6523x over previous
//
#include <hip/hip_runtime.h>
#include <hip/hip_bf16.h>
#include <hip/hip_fp16.h>

#define F_DIM 128
#define N_RBF 20
#define CUTOFF 5.0f
#define PI_F 3.14159265358979323846f
#define NPB 4   // nodes per k_edge block

typedef float v2f __attribute__((ext_vector_type(2)));
typedef __attribute__((ext_vector_type(8))) short bf16x8;
typedef __attribute__((ext_vector_type(4))) float f32x4;
typedef _Float16 h2f __attribute__((ext_vector_type(2)));
typedef _Float16 f16x8 __attribute__((ext_vector_type(8)));

__device__ __forceinline__ unsigned int bf16_rtne(float f) {
    unsigned int u = __float_as_uint(f);
    u += 0x7fffu + ((u >> 16) & 1u);
    return u >> 16;
}
__device__ __forceinline__ unsigned int pack_bf2(float lo, float hi) {
    return bf16_rtne(lo) | (bf16_rtne(hi) << 16);
}
__device__ __forceinline__ float unpk_lo(unsigned int u) {
    return __uint_as_float(u << 16);
}
__device__ __forceinline__ float unpk_hi(unsigned int u) {
    return __uint_as_float(u & 0xffff0000u);
}
__device__ __forceinline__ float bf16_to_f(unsigned short s) {
    return __uint_as_float(((unsigned int)s) << 16);
}
__device__ __forceinline__ unsigned int pack_h2(float lo, float hi) {
    h2f h = (h2f){(_Float16)lo, (_Float16)hi};
    return __builtin_bit_cast(unsigned int, h);
}
__device__ __forceinline__ unsigned short f16_bits(float f) {
    _Float16 h = (_Float16)f;
    return __builtin_bit_cast(unsigned short, h);
}
__device__ __forceinline__ float f16_to_f(unsigned short s) {
    return (float)__builtin_bit_cast(_Float16, s);
}

// ---------------------------------------------------------------------------
// Merged preprocessing: [0,nbR) rowptr | [nbR,nbR+nbG) geom | rest: weight prep.
__global__ __launch_bounds__(256) void k_pre(
        const int* __restrict__ idx_i, int* __restrict__ row_ptr,
        const float* __restrict__ r, unsigned int* __restrict__ geom,
        const float* __restrict__ muxW,
        const float* __restrict__ W1,
        const float* __restrict__ W2,
        const float* __restrict__ iW1,
        const float* __restrict__ iW2,
        const float* __restrict__ filt_W,
        const float* __restrict__ filt_b,
        unsigned short* __restrict__ muxWt,
        unsigned short* __restrict__ W1t,
        unsigned short* __restrict__ W2t,
        unsigned short* __restrict__ iW1t,
        unsigned short* __restrict__ iW2t,
        unsigned short* __restrict__ filtWt,
        int N, int E, int nbR, int nbG) {
    int bid = blockIdx.x;
    if (bid < nbR) {
        // ---- row_ptr via binary search ----
        int i = bid * 256 + threadIdx.x;
        if (i > N) return;
        if (i == N) { row_ptr[N] = E; return; }
        int lo = 0, hi = E;
        while (lo < hi) {
            int mid = (lo + hi) >> 1;
            if (idx_i[mid] < i) lo = mid + 1; else hi = mid;
        }
        row_ptr[i] = lo;
        return;
    }
    if (bid < nbR + nbG) {
        // ---- geometry record: 16 dwords/edge ----
        int e = (bid - nbR) * 256 + threadIdx.x;
        if (e >= E) return;
        float x = r[e * 3], y = r[e * 3 + 1], z = r[e * 3 + 2];
        float d = sqrtf(x * x + y * y + z * z);
        float inv = 1.f / d;
        float fc = (d < CUTOFF) ? 0.5f * (__cosf(d * (PI_F / CUTOFF)) + 1.f) : 0.f;
        unsigned int* g = geom + (size_t)e * 16;
        float dx = x * inv, dy = y * inv, dz = z * inv;
        g[0] = __float_as_uint(dx);
        g[1] = __float_as_uint(dy);
        g[2] = __float_as_uint(dz);
        g[3] = __float_as_uint(fc);
        const float delta = CUTOFF / (N_RBF - 1);
        const float coeff = -0.5f / (delta * delta);
        float ph[N_RBF];
#pragma unroll
        for (int k = 0; k < N_RBF; k++) {
            float t = d - k * delta;
            ph[k] = __expf(coeff * t * t) * fc;
        }
#pragma unroll
        for (int k = 0; k < N_RBF / 2; k++)
            g[4 + k] = pack_h2(ph[2 * k], ph[2 * k + 1]);
        g[14] = pack_h2(fc, dx);
        g[15] = pack_h2(dy, dz);
        return;
    }
    // ---- weight prep ----
    int idx = (bid - nbR - nbG) * 256 + threadIdx.x;
    if (idx < 98304) {                     // muxWt[l][c<256][k<128]
        int l = idx / 32768, rem = idx % 32768;
        int c = rem / 128, k = rem % 128;
        muxWt[idx] = (unsigned short)bf16_rtne(muxW[l * 32768 + k * 256 + c]);
    } else if (idx < 196608) {             // W1t[l][c<128][k<256]
        int i2 = idx - 98304;
        int l = i2 / 32768, rem = i2 % 32768;
        int c = rem / 256, k = rem % 256;
        W1t[i2] = (unsigned short)bf16_rtne(W1[l * 32768 + k * 128 + c]);
    } else if (idx < 344064) {             // W2t[l][c<384][k<128]
        int i2 = idx - 196608;
        int l = i2 / 49152, rem = i2 % 49152;
        int c = rem / 128, k = rem % 128;
        W2t[i2] = (unsigned short)bf16_rtne(W2[l * 49152 + k * 384 + c]);
    } else if (idx < 393216) {             // iW1t[l][c<128][k<128]
        int i2 = idx - 344064;
        int l = i2 / 16384, rem = i2 % 16384;
        int c = rem / 128, k = rem % 128;
        iW1t[i2] = (unsigned short)bf16_rtne(iW1[l * 16384 + k * 128 + c]);
    } else if (idx < 540672) {             // iW2t[l][c<384][k<128]
        int i2 = idx - 393216;
        int l = i2 / 49152, rem = i2 % 49152;
        int c = rem / 128, k = rem % 128;
        iW2t[i2] = (unsigned short)bf16_rtne(iW2[l * 49152 + k * 384 + c]);
    } else if (idx < 568320) {             // filtWt[l][c<384][k<24] f16
        int i2 = idx - 540672;
        int l = i2 / 9216, rem = i2 % 9216;
        int c = rem / 24, k = rem % 24;
        float v = 0.f;
        if (k < 20)       v = filt_W[k * 1152 + l * 384 + c];
        else if (k == 20) v = filt_b[l * 384 + c];
        _Float16 hv = (_Float16)v;
        filtWt[i2] = __builtin_bit_cast(unsigned short, hv);
    }
}

// ---------------------------------------------------------------------------
// Node message MLP via MFMA (layer 0 only), with q-init fused.
__global__ __launch_bounds__(256) void k_node_mfma(
        const int* __restrict__ Z,
        const float* __restrict__ emb,
        float* __restrict__ q,
        const unsigned short* __restrict__ iW1t,   // [128][128] bf16 (c,k)
        const float* __restrict__ b1,
        const unsigned short* __restrict__ iW2t,   // [384][128]
        const float* __restrict__ b2,
        unsigned int* __restrict__ P, int N) {
    __shared__ unsigned short A[16 * 136];
    __shared__ unsigned short Ah[16 * 136];
    __shared__ float Xs[16 * 396];
    int t = threadIdx.x;
    int w = t >> 6, l = t & 63, quad = l >> 4, c0 = l & 15;
    int n0 = blockIdx.x * 16;

#pragma unroll
    for (int i = 0; i < 4; i++) {
        int flat = i * 256 + t;
        int node = flat >> 6, cp = flat & 63;
        int gn = n0 + node;
        unsigned int v = 0u;
        if (gn < N) {
            const float* s = emb + (size_t)Z[gn] * 128 + 2 * cp;
            float s0 = s[0], s1 = s[1];
            v = pack_bf2(s0, s1);
            float* qo = q + (size_t)gn * 128 + 2 * cp;
            qo[0] = s0; qo[1] = s1;
        }
        *(unsigned int*)&A[node * 136 + 2 * cp] = v;
    }
    __syncthreads();

    bf16x8 a1[4];
#pragma unroll
    for (int ks = 0; ks < 4; ks++)
        a1[ks] = *(const bf16x8*)&A[c0 * 136 + ks * 32 + quad * 8];
#pragma unroll
    for (int jj = 0; jj < 2; jj++) {
        int jg = 2 * w + jj;
        float bb = b1[16 * jg + c0];
        f32x4 acc = (f32x4){bb, bb, bb, bb};
#pragma unroll
        for (int ks = 0; ks < 4; ks++) {
            bf16x8 b = *(const bf16x8*)&iW1t[(16 * jg + c0) * 128 + ks * 32 + quad * 8];
            acc = __builtin_amdgcn_mfma_f32_16x16x32_bf16(a1[ks], b, acc, 0, 0, 0);
        }
#pragma unroll
        for (int r = 0; r < 4; r++) {
            float aa = acc[r];
            Ah[(quad * 4 + r) * 136 + 16 * jg + c0] =
                (unsigned short)bf16_rtne(aa / (1.f + __expf(-aa)));
        }
    }
    __syncthreads();

    bf16x8 a3[4];
#pragma unroll
    for (int ks = 0; ks < 4; ks++)
        a3[ks] = *(const bf16x8*)&Ah[c0 * 136 + ks * 32 + quad * 8];
#pragma unroll
    for (int jj = 0; jj < 6; jj++) {
        int jx = 6 * w + jj;
        float bb = b2[16 * jx + c0];
        f32x4 acc = (f32x4){bb, bb, bb, bb};
#pragma unroll
        for (int ks = 0; ks < 4; ks++) {
            bf16x8 b = *(const bf16x8*)&iW2t[(16 * jx + c0) * 128 + ks * 32 + quad * 8];
            acc = __builtin_amdgcn_mfma_f32_16x16x32_bf16(a3[ks], b, acc, 0, 0, 0);
        }
#pragma unroll
        for (int r = 0; r < 4; r++)
            Xs[(quad * 4 + r) * 396 + 16 * jx + c0] = acc[r];
    }
    __syncthreads();

    int n = t >> 4, fi = (t & 15) * 8;
    int gn = n0 + n;
    if (gn < N) {
        size_t base = (size_t)gn * 384;
        unsigned int d[8];
#pragma unroll
        for (int k = 0; k < 8; k++) {
            float x0 = Xs[n * 396 + fi + k];
            float x1 = Xs[n * 396 + 128 + fi + k];
            float x2 = Xs[n * 396 + 256 + fi + k];
            d[k] = pack_bf2(x0, x1);
            ((unsigned short*)&P[base + 256 + fi + k])[0] = (unsigned short)bf16_rtne(x2);
        }
        *(uint4*)&P[base + fi]     = make_uint4(d[0], d[1], d[2], d[3]);
        *(uint4*)&P[base + fi + 4] = make_uint4(d[4], d[5], d[6], d[7]);
    }
}

// ---------------------------------------------------------------------------
// A-frag loader for the filter MFMA: 24 f16 channels at geom dwords 4..15,
// K padded to 32 (quad 3 = zeros).
__device__ __forceinline__ f16x8 load_phi_frag(const unsigned int* __restrict__ geom,
                                               int ts, int c0, int quad, int E) {
    int ea = ts + c0;
    if (ea >= E) ea = E - 1;          // clamp; pad rows are never aggregated
    f16x8 a = {};
    if (quad < 3)
        a = *(const f16x8*)&geom[(size_t)ea * 16 + 4 + quad * 4];
    return a;
}

// ---------------------------------------------------------------------------
// Edge aggregation — FINAL form (reverted to the R5-proven version).
// Evidence this is at its pattern roofline: four structurally different
// schedules (serial fdot2, MFMA-tile, 24-deep register pipeline at 20% occ,
// f16-LDS at 53% occ) all converge on ~220 MB FETCH at ~2.6-2.8 TB/s for
// the random 1536B-row gather of the L3-resident P table; R2 proved that
// 8x more outstanding requests does NOT help (request-pattern bound, not
// latency bound), and R7 proved register-pipelining past 64 VGPR spills
// to scratch (+600 MB traffic).
template <bool HAS_MU>
__global__ __launch_bounds__(256, 8) void k_edge(
        const unsigned int* __restrict__ P,
        const unsigned int* __restrict__ geom,
        const int* __restrict__ idx_j,
        const int* __restrict__ row_ptr,
        const unsigned short* __restrict__ filtWt,  // [384][24] f16 (layer slice)
        float* __restrict__ q,
        float* __restrict__ muD, int N, int E) {
    constexpr int NT = HAS_MU ? 6 : 4;     // 16-col tiles per wave (24 or 16 total)
    constexpr int WS = HAS_MU ? 412 : 268; // ushort row stride
    __shared__ unsigned short Ws[16 * WS];
    __shared__ float red[4][128];
    int t = threadIdx.x;
    int f = t & 127;
    int sub = __builtin_amdgcn_readfirstlane(t >> 7);
    int w = t >> 6, l = t & 63, quad = l >> 4, c0 = l & 15;

    f16x8 Bf[NT];
#pragma unroll
    for (int jj = 0; jj < NT; jj++) {
        int jx = NT * w + jj;
        f16x8 b = {};
        if (quad < 3)
            b = *(const f16x8*)&filtWt[(16 * jx + c0) * 24 + quad * 8];
        Bf[jj] = b;
    }

    int i0 = blockIdx.x * NPB;
    for (int nn = 0; nn < NPB; nn++) {
        int i = i0 + nn;
        if (i >= N) break;
        int rs = __builtin_amdgcn_readfirstlane(row_ptr[i]);
        int re = __builtin_amdgcn_readfirstlane(row_ptr[i + 1]);
        float dq = 0.f;
        v2f dm01 = (v2f){0.f, 0.f};
        float dm2 = 0.f;

        f16x8 a = load_phi_frag(geom, rs, c0, quad, E);
        for (int ts = rs; ts < re; ts += 16) {
#pragma unroll
            for (int jj = 0; jj < NT; jj++) {
                int jx = NT * w + jj;
                f32x4 acc = (f32x4){0.f, 0.f, 0.f, 0.f};
                acc = __builtin_amdgcn_mfma_f32_16x16x32_f16(a, Bf[jj], acc, 0, 0, 0);
#pragma unroll
                for (int r = 0; r < 4; r++)
                    Ws[(quad * 4 + r) * WS + 16 * jx + c0] = f16_bits(acc[r]);
            }
            __syncthreads();
            if (ts + 16 < re) a = load_phi_frag(geom, ts + 16, c0, quad, E);

            int te = (re < ts + 16) ? re : ts + 16;
            for (int e = ts + sub; e < te; e += 2) {
                int j = __builtin_amdgcn_readfirstlane(idx_j[e]);
                const unsigned int* Pj = P + (size_t)j * 384;
                unsigned int A = Pj[f];
                unsigned int B = 0, C = 0;
                if (HAS_MU) { B = Pj[128 + f]; C = Pj[256 + f]; }

                const float* g = (const float*)(geom + (size_t)e * 16);
                float dirx = g[0], diry = g[1], dirz = g[2];

                int eloc = e - ts;
                float wq = f16_to_f(Ws[eloc * WS + f]);
                float wr = f16_to_f(Ws[eloc * WS + 128 + f]);

                float xq = unpk_lo(A), xr = unpk_hi(A);
                dq += wq * xq;
                float s_r = wr * xr;
                if (HAS_MU) {
                    float wm = f16_to_f(Ws[eloc * WS + 256 + f]);
                    float xm = unpk_lo(C);
                    float s_m = wm * xm;
                    dm01 += (v2f){s_r, s_r} * (v2f){dirx, diry} +
                            (v2f){s_m, s_m} * (v2f){unpk_lo(B), unpk_hi(B)};
                    dm2  += s_r * dirz + s_m * unpk_hi(C);
                } else {
                    dm01 += (v2f){s_r, s_r} * (v2f){dirx, diry};
                    dm2  += s_r * dirz;
                }
            }
            __syncthreads();
        }

        if (sub == 1) { red[0][f] = dq; red[1][f] = dm01.x; red[2][f] = dm01.y; red[3][f] = dm2; }
        __syncthreads();
        if (sub == 0) {
            dq += red[0][f];
            float d0 = dm01.x + red[1][f], d1 = dm01.y + red[2][f];
            dm2 += red[3][f];
            q[(size_t)i * 128 + f] += dq;
            size_t base = (size_t)i * 384;
            if (HAS_MU) {
                muD[base + f]       += d0;
                muD[base + 128 + f] += d1;
                muD[base + 256 + f] += dm2;
            } else {   // layer 0: mu starts at zero
                muD[base + f]       = d0;
                muD[base + 128 + f] = d1;
                muD[base + 256 + f] = dm2;
            }
        }
        __syncthreads();
    }
}

// ---------------------------------------------------------------------------
// Fused mixing(l) + node-message(l+1). One-shot mu_mix (48 MFMAs, 8 barriers),
// 54144 B LDS -> 3 blocks/CU.
__global__ __launch_bounds__(256, 3) void k_mix_fused(
        float* __restrict__ q, float* __restrict__ mu,
        const unsigned short* __restrict__ muxWt,   // [256][128] bf16 (c,k)
        const unsigned short* __restrict__ W1t,     // [128][256]
        const unsigned short* __restrict__ W2t,     // [384][128]
        const float* __restrict__ b1,
        const float* __restrict__ b2,
        const unsigned short* __restrict__ niW1t,   // next-layer node W1t
        const float* __restrict__ nib1,
        const unsigned short* __restrict__ niW2t,   // next-layer node W2t
        const float* __restrict__ nib2,
        int has_node,
        unsigned int* __restrict__ P, int N) {
    constexpr int XS = 516;                         // f32 row stride; S at +388
    __shared__ __align__(16) unsigned char LDSm[54144];
    unsigned short* A   = (unsigned short*)LDSm;             // [16][264] bf16
    unsigned short* Wsp = (unsigned short*)(LDSm + 8448);    // [3][16][132] bf16
    float*          Xs  = (float*)(LDSm + 21120);            // [16][516] f32
    unsigned short* Amu = (unsigned short*)(LDSm + 21120);   // [48][136] (aliases Xs)

    int t = threadIdx.x;
    int w = t >> 6, l = t & 63, quad = l >> 4, c0 = l & 15;
    int n0 = blockIdx.x * 16;

    // ---- single staging phase: q -> A[:, 0..128), mu -> Amu[48][128] ----
#pragma unroll
    for (int i = 0; i < 4; i++) {
        int flat = i * 256 + t;
        int node = flat >> 6, cp = flat & 63, gn = n0 + node;
        unsigned int v = 0u;
        if (gn < N) { const float* s = q + (size_t)gn * 128 + 2 * cp; v = pack_bf2(s[0], s[1]); }
        *(unsigned int*)&A[node * 264 + 2 * cp] = v;
    }
#pragma unroll
    for (int i = 0; i < 12; i++) {
        int flat = i * 256 + t;
        int row = flat >> 6, cp = flat & 63;
        int node = row & 15, c = row >> 4, gn = n0 + node;
        unsigned int v = 0u;
        if (gn < N) {
            const float* s = mu + (size_t)gn * 384 + c * 128 + 2 * cp;
            v = pack_bf2(s[0], s[1]);
        }
        *(unsigned int*)&Amu[row * 136 + 2 * cp] = v;
    }
    __syncthreads();                                              // B1

    // ---- one-shot mu_mix: 48 MFMAs, vn2/S in regs, Wm -> Wsp ----
    f32x4 vn2[2], S[2];
#pragma unroll
    for (int jj = 0; jj < 2; jj++) { vn2[jj] = (f32x4){0,0,0,0}; S[jj] = (f32x4){0,0,0,0}; }
#pragma unroll
    for (int rt = 0; rt < 3; rt++) {
        bf16x8 af[4];
#pragma unroll
        for (int ks = 0; ks < 4; ks++)
            af[ks] = *(const bf16x8*)&Amu[(rt * 16 + c0) * 136 + ks * 32 + quad * 8];
#pragma unroll
        for (int jj = 0; jj < 2; jj++) {
            int jv = 2 * w + jj;
            f32x4 V = (f32x4){0,0,0,0}, Wm = (f32x4){0,0,0,0};
#pragma unroll
            for (int ks = 0; ks < 4; ks++) {
                bf16x8 bV = *(const bf16x8*)&muxWt[(16 * jv + c0) * 128 + ks * 32 + quad * 8];
                V = __builtin_amdgcn_mfma_f32_16x16x32_bf16(af[ks], bV, V, 0, 0, 0);
            }
#pragma unroll
            for (int ks = 0; ks < 4; ks++) {
                bf16x8 bW = *(const bf16x8*)&muxWt[(16 * (jv + 8) + c0) * 128 + ks * 32 + quad * 8];
                Wm = __builtin_amdgcn_mfma_f32_16x16x32_bf16(af[ks], bW, Wm, 0, 0, 0);
            }
            vn2[jj] += V * V;
            S[jj]   += V * Wm;
#pragma unroll
            for (int r = 0; r < 4; r++)
                Wsp[rt * 2112 + (quad * 4 + r) * 132 + 16 * jv + c0] =
                    (unsigned short)bf16_rtne(Wm[r]);
        }
    }
    // mu_Vn -> A[:, 128..256) (ctx second half)
#pragma unroll
    for (int jj = 0; jj < 2; jj++) {
        int jv = 2 * w + jj;
#pragma unroll
        for (int r = 0; r < 4; r++)
            A[(quad * 4 + r) * 264 + 128 + 16 * jv + c0] =
                (unsigned short)bf16_rtne(sqrtf(vn2[jj][r] + 1e-8f));
    }
    __syncthreads();                                              // B2

    bf16x8 a2[8];
#pragma unroll
    for (int ks = 0; ks < 8; ks++)
        a2[ks] = *(const bf16x8*)&A[c0 * 264 + ks * 32 + quad * 8];
    {
        unsigned short htmp[2][4];
#pragma unroll
        for (int jj = 0; jj < 2; jj++) {
            int jg = 2 * w + jj;
            float bb = b1[16 * jg + c0];
            f32x4 acc = (f32x4){bb, bb, bb, bb};
#pragma unroll
            for (int ks = 0; ks < 8; ks++) {
                bf16x8 b = *(const bf16x8*)&W1t[(16 * jg + c0) * 256 + ks * 32 + quad * 8];
                acc = __builtin_amdgcn_mfma_f32_16x16x32_bf16(a2[ks], b, acc, 0, 0, 0);
            }
#pragma unroll
            for (int r = 0; r < 4; r++) {
                float aa = acc[r];
                htmp[jj][r] = (unsigned short)bf16_rtne(aa / (1.f + __expf(-aa)));
            }
        }
        __syncthreads();                                          // B3 (WAR vs a2)
#pragma unroll
        for (int jj = 0; jj < 2; jj++) {
            int jg = 2 * w + jj;
#pragma unroll
            for (int r = 0; r < 4; r++)
                A[(quad * 4 + r) * 264 + 128 + 16 * jg + c0] = htmp[jj][r];
        }
    }
    __syncthreads();                                              // B4

    bf16x8 a3[4];
#pragma unroll
    for (int ks = 0; ks < 4; ks++)
        a3[ks] = *(const bf16x8*)&A[c0 * 264 + 128 + ks * 32 + quad * 8];
#pragma unroll
    for (int jj = 0; jj < 6; jj++) {
        int jx = 6 * w + jj;
        float bb = b2[16 * jx + c0];
        f32x4 acc = (f32x4){bb, bb, bb, bb};
#pragma unroll
        for (int ks = 0; ks < 4; ks++) {
            bf16x8 b = *(const bf16x8*)&W2t[(16 * jx + c0) * 128 + ks * 32 + quad * 8];
            acc = __builtin_amdgcn_mfma_f32_16x16x32_bf16(a3[ks], b, acc, 0, 0, 0);
        }
#pragma unroll
        for (int r = 0; r < 4; r++)
            Xs[(quad * 4 + r) * XS + 16 * jx + c0] = acc[r];
    }
#pragma unroll
    for (int jj = 0; jj < 2; jj++) {
        int jv = 2 * w + jj;
#pragma unroll
        for (int r = 0; r < 4; r++)
            Xs[(quad * 4 + r) * XS + 388 + 16 * jv + c0] = S[jj][r];
    }
    __syncthreads();                                              // B5

    int n = t >> 4, fi = (t & 15) * 8;
    int gn = n0 + n;
    if (gn < N) {
        float* qp = q + (size_t)gn * 128 + fi;
        float qn[8];
#pragma unroll
        for (int k = 0; k < 8; k++) {
            qn[k] = qp[k] + Xs[n * XS + fi + k] +
                    Xs[n * XS + 256 + fi + k] * Xs[n * XS + 388 + fi + k];
            qp[k] = qn[k];
        }
        unsigned int qd[4];
#pragma unroll
        for (int p = 0; p < 4; p++) qd[p] = pack_bf2(qn[2 * p], qn[2 * p + 1]);
        *(uint4*)&A[n * 264 + fi] = make_uint4(qd[0], qd[1], qd[2], qd[3]);

        size_t base = (size_t)gn * 384;
        float m[3][8];
#pragma unroll
        for (int c = 0; c < 3; c++) {
            float* mp = mu + base + c * 128 + fi;
#pragma unroll
            for (int k = 0; k < 8; k++) {
                m[c][k] = mp[k] + Xs[n * XS + 128 + fi + k] *
                                  bf16_to_f(Wsp[c * 2112 + n * 132 + fi + k]);
                mp[k] = m[c][k];
            }
        }
        if (has_node) {   // P mu-rows only consumed by the next edge layer
            unsigned int d[8];
#pragma unroll
            for (int k = 0; k < 8; k++) {
                d[k] = pack_bf2(m[0][k], m[1][k]);
                ((unsigned short*)&P[base + 256 + fi + k])[1] = (unsigned short)bf16_rtne(m[2][k]);
            }
            *(uint4*)&P[base + 128 + fi]     = make_uint4(d[0], d[1], d[2], d[3]);
            *(uint4*)&P[base + 128 + fi + 4] = make_uint4(d[4], d[5], d[6], d[7]);
        }
    }
    __syncthreads();                                              // B6

    if (has_node) {
        unsigned short* Ah = Wsp;   // reuse (Wsp reads finished at B6)
        bf16x8 a1[4];
#pragma unroll
        for (int ks = 0; ks < 4; ks++)
            a1[ks] = *(const bf16x8*)&A[c0 * 264 + ks * 32 + quad * 8];
#pragma unroll
        for (int jj = 0; jj < 2; jj++) {
            int jg = 2 * w + jj;
            float bb = nib1[16 * jg + c0];
            f32x4 acc = (f32x4){bb, bb, bb, bb};
#pragma unroll
            for (int ks = 0; ks < 4; ks++) {
                bf16x8 b = *(const bf16x8*)&niW1t[(16 * jg + c0) * 128 + ks * 32 + quad * 8];
                acc = __builtin_amdgcn_mfma_f32_16x16x32_bf16(a1[ks], b, acc, 0, 0, 0);
            }
#pragma unroll
            for (int r = 0; r < 4; r++) {
                float aa = acc[r];
                Ah[(quad * 4 + r) * 136 + 16 * jg + c0] =
                    (unsigned short)bf16_rtne(aa / (1.f + __expf(-aa)));
            }
        }
        __syncthreads();                                          // B7

        bf16x8 a4[4];
#pragma unroll
        for (int ks = 0; ks < 4; ks++)
            a4[ks] = *(const bf16x8*)&Ah[c0 * 136 + ks * 32 + quad * 8];
#pragma unroll
        for (int jj = 0; jj < 6; jj++) {
            int jx = 6 * w + jj;
            float bb = nib2[16 * jx + c0];
            f32x4 acc = (f32x4){bb, bb, bb, bb};
#pragma unroll
            for (int ks = 0; ks < 4; ks++) {
                bf16x8 b = *(const bf16x8*)&niW2t[(16 * jx + c0) * 128 + ks * 32 + quad * 8];
                acc = __builtin_amdgcn_mfma_f32_16x16x32_bf16(a4[ks], b, acc, 0, 0, 0);
            }
#pragma unroll
            for (int r = 0; r < 4; r++)
                Xs[(quad * 4 + r) * XS + 16 * jx + c0] = acc[r];
        }
        __syncthreads();                                          // B8

        if (gn < N) {
            size_t base = (size_t)gn * 384;
            unsigned int d[8];
#pragma unroll
            for (int k = 0; k < 8; k++) {
                float x0 = Xs[n * XS + fi + k];
                float x1 = Xs[n * XS + 128 + fi + k];
                float x2 = Xs[n * XS + 256 + fi + k];
                d[k] = pack_bf2(x0, x1);
                ((unsigned short*)&P[base + 256 + fi + k])[0] = (unsigned short)bf16_rtne(x2);
            }
            *(uint4*)&P[base + fi]     = make_uint4(d[0], d[1], d[2], d[3]);
            *(uint4*)&P[base + fi + 4] = make_uint4(d[4], d[5], d[6], d[7]);
        }
    }
}

// ---------------------------------------------------------------------------
extern "C" void kernel_launch(void* const* d_in, const int* in_sizes, int n_in,
                              void* d_out, int out_size, void* d_ws, size_t ws_size,
                              hipStream_t stream) {
    const int*   Z      = (const int*)d_in[0];
    const float* r_ij   = (const float*)d_in[1];
    const int*   idx_i  = (const int*)d_in[2];
    const int*   idx_j  = (const int*)d_in[3];
    const float* emb    = (const float*)d_in[4];
    const float* filt_W = (const float*)d_in[5];
    const float* filt_b = (const float*)d_in[6];
    const float* int_W1 = (const float*)d_in[7];
    const float* int_b1 = (const float*)d_in[8];
    const float* int_W2 = (const float*)d_in[9];
    const float* int_b2 = (const float*)d_in[10];
    const float* mix_W1 = (const float*)d_in[11];
    const float* mix_b1 = (const float*)d_in[12];
    const float* mix_W2 = (const float*)d_in[13];
    const float* mix_b2 = (const float*)d_in[14];
    const float* mux_W  = (const float*)d_in[15];

    int N = in_sizes[0];
    int E = in_sizes[2];

    float* q   = (float*)d_out;              // [N,128]  q state (fp32)
    float* muD = q + (size_t)N * 128;        // [N,3,128] mu state (fp32)

    unsigned int* geom = (unsigned int*)d_ws;                 // E*16 u32 (64 B/edge)
    unsigned int* P = geom + (size_t)E * 16;                  // N*384 u32
    int* row_ptr = (int*)(P + (size_t)N * 384);               // N+1
    uintptr_t waddr = (uintptr_t)(row_ptr + N + 1);
    waddr = (waddr + 15) & ~(uintptr_t)15;
    unsigned short* muxWt = (unsigned short*)waddr;   // 3*256*128
    unsigned short* W1t   = muxWt + 98304;            // 3*128*256
    unsigned short* W2t   = W1t + 98304;              // 3*384*128
    unsigned short* iW1t  = W2t + 147456;             // 3*128*128
    unsigned short* iW2t  = iW1t + 49152;             // 3*384*128
    unsigned short* filtWt = iW2t + 147456;           // 3*384*24 f16

    int nbR = (N + 1 + 255) / 256;
    int nbG = (E + 255) / 256;
    k_pre<<<nbR + nbG + 2220, 256, 0, stream>>>(
        idx_i, row_ptr, r_ij, geom,
        mux_W, mix_W1, mix_W2, int_W1, int_W2, filt_W, filt_b,
        muxWt, W1t, W2t, iW1t, iW2t, filtWt, N, E, nbR, nbG);

    int tiles = (N + 15) / 16;
    k_node_mfma<<<tiles, 256, 0, stream>>>(
        Z, emb, q, iW1t, int_b1, iW2t, int_b2, P, N);
    for (int l = 0; l < 3; l++) {
        if (l == 0)
            k_edge<false><<<(N + NPB - 1) / NPB, 256, 0, stream>>>(
                P, geom, idx_j, row_ptr, filtWt, q, muD, N, E);
        else
            k_edge<true><<<(N + NPB - 1) / NPB, 256, 0, stream>>>(
                P, geom, idx_j, row_ptr, filtWt + (size_t)l * 9216, q, muD, N, E);
        int nl = (l < 2) ? (l + 1) : 0;
        k_mix_fused<<<tiles, 256, 0, stream>>>(
            q, muD, muxWt + (size_t)l * 32768, W1t + (size_t)l * 32768,
            W2t + (size_t)l * 49152, mix_b1 + l * 128, mix_b2 + l * 384,
            iW1t + (size_t)nl * 16384, int_b1 + nl * 128,
            iW2t + (size_t)nl * 49152, int_b2 + nl * 384,
            (l < 2) ? 1 : 0, P, N);
    }
    // q in d_out; final mu (fp32 state) in muD = d_out mu region.
}

// Round 9
// 501.675 us; speedup vs baseline: 1.7554x; 1.0624x over previous
//
#include <hip/hip_runtime.h>
#include <hip/hip_bf16.h>
#include <hip/hip_fp16.h>

#define F_DIM 128
#define N_RBF 20
#define CUTOFF 5.0f
#define PI_F 3.14159265358979323846f
#define NPB 4   // nodes per k_edge block

typedef float v2f __attribute__((ext_vector_type(2)));
typedef __attribute__((ext_vector_type(8))) short bf16x8;
typedef __attribute__((ext_vector_type(4))) float f32x4;
typedef _Float16 h2f __attribute__((ext_vector_type(2)));
typedef _Float16 f16x8 __attribute__((ext_vector_type(8)));

__device__ __forceinline__ unsigned int bf16_rtne(float f) {
    unsigned int u = __float_as_uint(f);
    u += 0x7fffu + ((u >> 16) & 1u);
    return u >> 16;
}
__device__ __forceinline__ unsigned int pack_bf2(float lo, float hi) {
    return bf16_rtne(lo) | (bf16_rtne(hi) << 16);
}
__device__ __forceinline__ float unpk_lo(unsigned int u) {
    return __uint_as_float(u << 16);
}
__device__ __forceinline__ float unpk_hi(unsigned int u) {
    return __uint_as_float(u & 0xffff0000u);
}
__device__ __forceinline__ float bf16_to_f(unsigned short s) {
    return __uint_as_float(((unsigned int)s) << 16);
}
__device__ __forceinline__ unsigned int pack_h2(float lo, float hi) {
    h2f h = (h2f){(_Float16)lo, (_Float16)hi};
    return __builtin_bit_cast(unsigned int, h);
}
__device__ __forceinline__ unsigned short f16_bits(float f) {
    _Float16 h = (_Float16)f;
    return __builtin_bit_cast(unsigned short, h);
}
__device__ __forceinline__ float f16_to_f(unsigned short s) {
    return (float)__builtin_bit_cast(_Float16, s);
}

// ---------------------------------------------------------------------------
// Merged preprocessing: [0,nbR) rowptr | [nbR,nbR+nbG) geom | rest: weight prep.
__global__ __launch_bounds__(256) void k_pre(
        const int* __restrict__ idx_i, int* __restrict__ row_ptr,
        const float* __restrict__ r, unsigned int* __restrict__ geom,
        const float* __restrict__ muxW,
        const float* __restrict__ W1,
        const float* __restrict__ W2,
        const float* __restrict__ iW1,
        const float* __restrict__ iW2,
        const float* __restrict__ filt_W,
        const float* __restrict__ filt_b,
        unsigned short* __restrict__ muxWt,
        unsigned short* __restrict__ W1t,
        unsigned short* __restrict__ W2t,
        unsigned short* __restrict__ iW1t,
        unsigned short* __restrict__ iW2t,
        unsigned short* __restrict__ filtWt,
        int N, int E, int nbR, int nbG) {
    int bid = blockIdx.x;
    if (bid < nbR) {
        // ---- row_ptr via binary search ----
        int i = bid * 256 + threadIdx.x;
        if (i > N) return;
        if (i == N) { row_ptr[N] = E; return; }
        int lo = 0, hi = E;
        while (lo < hi) {
            int mid = (lo + hi) >> 1;
            if (idx_i[mid] < i) lo = mid + 1; else hi = mid;
        }
        row_ptr[i] = lo;
        return;
    }
    if (bid < nbR + nbG) {
        // ---- geometry record: 16 dwords/edge ----
        int e = (bid - nbR) * 256 + threadIdx.x;
        if (e >= E) return;
        float x = r[e * 3], y = r[e * 3 + 1], z = r[e * 3 + 2];
        float d = sqrtf(x * x + y * y + z * z);
        float inv = 1.f / d;
        float fc = (d < CUTOFF) ? 0.5f * (__cosf(d * (PI_F / CUTOFF)) + 1.f) : 0.f;
        unsigned int* g = geom + (size_t)e * 16;
        float dx = x * inv, dy = y * inv, dz = z * inv;
        g[0] = __float_as_uint(dx);
        g[1] = __float_as_uint(dy);
        g[2] = __float_as_uint(dz);
        g[3] = __float_as_uint(fc);
        const float delta = CUTOFF / (N_RBF - 1);
        const float coeff = -0.5f / (delta * delta);
        float ph[N_RBF];
#pragma unroll
        for (int k = 0; k < N_RBF; k++) {
            float t = d - k * delta;
            ph[k] = __expf(coeff * t * t) * fc;
        }
#pragma unroll
        for (int k = 0; k < N_RBF / 2; k++)
            g[4 + k] = pack_h2(ph[2 * k], ph[2 * k + 1]);
        g[14] = pack_h2(fc, dx);
        g[15] = pack_h2(dy, dz);
        return;
    }
    // ---- weight prep ----
    int idx = (bid - nbR - nbG) * 256 + threadIdx.x;
    if (idx < 98304) {                     // muxWt[l][c<256][k<128]
        int l = idx / 32768, rem = idx % 32768;
        int c = rem / 128, k = rem % 128;
        muxWt[idx] = (unsigned short)bf16_rtne(muxW[l * 32768 + k * 256 + c]);
    } else if (idx < 196608) {             // W1t[l][c<128][k<256]
        int i2 = idx - 98304;
        int l = i2 / 32768, rem = i2 % 32768;
        int c = rem / 256, k = rem % 256;
        W1t[i2] = (unsigned short)bf16_rtne(W1[l * 32768 + k * 128 + c]);
    } else if (idx < 344064) {             // W2t[l][c<384][k<128]
        int i2 = idx - 196608;
        int l = i2 / 49152, rem = i2 % 49152;
        int c = rem / 128, k = rem % 128;
        W2t[i2] = (unsigned short)bf16_rtne(W2[l * 49152 + k * 384 + c]);
    } else if (idx < 393216) {             // iW1t[l][c<128][k<128]
        int i2 = idx - 344064;
        int l = i2 / 16384, rem = i2 % 16384;
        int c = rem / 128, k = rem % 128;
        iW1t[i2] = (unsigned short)bf16_rtne(iW1[l * 16384 + k * 128 + c]);
    } else if (idx < 540672) {             // iW2t[l][c<384][k<128]
        int i2 = idx - 393216;
        int l = i2 / 49152, rem = i2 % 49152;
        int c = rem / 128, k = rem % 128;
        iW2t[i2] = (unsigned short)bf16_rtne(iW2[l * 49152 + k * 384 + c]);
    } else if (idx < 568320) {             // filtWt[l][c<384][k<24] f16
        int i2 = idx - 540672;
        int l = i2 / 9216, rem = i2 % 9216;
        int c = rem / 24, k = rem % 24;
        float v = 0.f;
        if (k < 20)       v = filt_W[k * 1152 + l * 384 + c];
        else if (k == 20) v = filt_b[l * 384 + c];
        _Float16 hv = (_Float16)v;
        filtWt[i2] = __builtin_bit_cast(unsigned short, hv);
    }
}

// ---------------------------------------------------------------------------
// Node message MLP via MFMA (layer 0 only), with q-init fused.
__global__ __launch_bounds__(256) void k_node_mfma(
        const int* __restrict__ Z,
        const float* __restrict__ emb,
        float* __restrict__ q,
        const unsigned short* __restrict__ iW1t,   // [128][128] bf16 (c,k)
        const float* __restrict__ b1,
        const unsigned short* __restrict__ iW2t,   // [384][128]
        const float* __restrict__ b2,
        unsigned int* __restrict__ P, int N) {
    __shared__ unsigned short A[16 * 136];
    __shared__ unsigned short Ah[16 * 136];
    __shared__ float Xs[16 * 396];
    int t = threadIdx.x;
    int w = t >> 6, l = t & 63, quad = l >> 4, c0 = l & 15;
    int n0 = blockIdx.x * 16;

#pragma unroll
    for (int i = 0; i < 4; i++) {
        int flat = i * 256 + t;
        int node = flat >> 6, cp = flat & 63;
        int gn = n0 + node;
        unsigned int v = 0u;
        if (gn < N) {
            const float* s = emb + (size_t)Z[gn] * 128 + 2 * cp;
            float s0 = s[0], s1 = s[1];
            v = pack_bf2(s0, s1);
            float* qo = q + (size_t)gn * 128 + 2 * cp;
            qo[0] = s0; qo[1] = s1;
        }
        *(unsigned int*)&A[node * 136 + 2 * cp] = v;
    }
    __syncthreads();

    bf16x8 a1[4];
#pragma unroll
    for (int ks = 0; ks < 4; ks++)
        a1[ks] = *(const bf16x8*)&A[c0 * 136 + ks * 32 + quad * 8];
#pragma unroll
    for (int jj = 0; jj < 2; jj++) {
        int jg = 2 * w + jj;
        float bb = b1[16 * jg + c0];
        f32x4 acc = (f32x4){bb, bb, bb, bb};
#pragma unroll
        for (int ks = 0; ks < 4; ks++) {
            bf16x8 b = *(const bf16x8*)&iW1t[(16 * jg + c0) * 128 + ks * 32 + quad * 8];
            acc = __builtin_amdgcn_mfma_f32_16x16x32_bf16(a1[ks], b, acc, 0, 0, 0);
        }
#pragma unroll
        for (int r = 0; r < 4; r++) {
            float aa = acc[r];
            Ah[(quad * 4 + r) * 136 + 16 * jg + c0] =
                (unsigned short)bf16_rtne(aa / (1.f + __expf(-aa)));
        }
    }
    __syncthreads();

    bf16x8 a3[4];
#pragma unroll
    for (int ks = 0; ks < 4; ks++)
        a3[ks] = *(const bf16x8*)&Ah[c0 * 136 + ks * 32 + quad * 8];
#pragma unroll
    for (int jj = 0; jj < 6; jj++) {
        int jx = 6 * w + jj;
        float bb = b2[16 * jx + c0];
        f32x4 acc = (f32x4){bb, bb, bb, bb};
#pragma unroll
        for (int ks = 0; ks < 4; ks++) {
            bf16x8 b = *(const bf16x8*)&iW2t[(16 * jx + c0) * 128 + ks * 32 + quad * 8];
            acc = __builtin_amdgcn_mfma_f32_16x16x32_bf16(a3[ks], b, acc, 0, 0, 0);
        }
#pragma unroll
        for (int r = 0; r < 4; r++)
            Xs[(quad * 4 + r) * 396 + 16 * jx + c0] = acc[r];
    }
    __syncthreads();

    int n = t >> 4, fi = (t & 15) * 8;
    int gn = n0 + n;
    if (gn < N) {
        size_t base = (size_t)gn * 384;
        unsigned int d[8];
#pragma unroll
        for (int k = 0; k < 8; k++) {
            float x0 = Xs[n * 396 + fi + k];
            float x1 = Xs[n * 396 + 128 + fi + k];
            float x2 = Xs[n * 396 + 256 + fi + k];
            d[k] = pack_bf2(x0, x1);
            ((unsigned short*)&P[base + 256 + fi + k])[0] = (unsigned short)bf16_rtne(x2);
        }
        *(uint4*)&P[base + fi]     = make_uint4(d[0], d[1], d[2], d[3]);
        *(uint4*)&P[base + fi + 4] = make_uint4(d[4], d[5], d[6], d[7]);
    }
}

// ---------------------------------------------------------------------------
// A-frag loader for the filter MFMA: 24 f16 channels at geom dwords 4..15,
// K padded to 32 (quad 3 = zeros).
__device__ __forceinline__ f16x8 load_phi_frag(const unsigned int* __restrict__ geom,
                                               int ts, int c0, int quad, int E) {
    int ea = ts + c0;
    if (ea >= E) ea = E - 1;          // clamp; pad rows are never aggregated
    f16x8 a = {};
    if (quad < 3)
        a = *(const f16x8*)&geom[(size_t)ea * 16 + 4 + quad * 4];
    return a;
}

// ---------------------------------------------------------------------------
// Edge aggregation — FINAL form (R5/R8-proven, at the random-row gather
// pattern ceiling: four structural variants converge on ~220 MB FETCH at
// ~2.6-2.8 TB/s; more outstanding requests does not help (R2), and
// register-pipelining past 64 VGPR spills (R7)).
template <bool HAS_MU>
__global__ __launch_bounds__(256, 8) void k_edge(
        const unsigned int* __restrict__ P,
        const unsigned int* __restrict__ geom,
        const int* __restrict__ idx_j,
        const int* __restrict__ row_ptr,
        const unsigned short* __restrict__ filtWt,  // [384][24] f16 (layer slice)
        float* __restrict__ q,
        float* __restrict__ muD, int N, int E) {
    constexpr int NT = HAS_MU ? 6 : 4;     // 16-col tiles per wave (24 or 16 total)
    constexpr int WS = HAS_MU ? 412 : 268; // ushort row stride
    __shared__ unsigned short Ws[16 * WS];
    __shared__ float red[4][128];
    int t = threadIdx.x;
    int f = t & 127;
    int sub = __builtin_amdgcn_readfirstlane(t >> 7);
    int w = t >> 6, l = t & 63, quad = l >> 4, c0 = l & 15;

    f16x8 Bf[NT];
#pragma unroll
    for (int jj = 0; jj < NT; jj++) {
        int jx = NT * w + jj;
        f16x8 b = {};
        if (quad < 3)
            b = *(const f16x8*)&filtWt[(16 * jx + c0) * 24 + quad * 8];
        Bf[jj] = b;
    }

    int i0 = blockIdx.x * NPB;
    for (int nn = 0; nn < NPB; nn++) {
        int i = i0 + nn;
        if (i >= N) break;
        int rs = __builtin_amdgcn_readfirstlane(row_ptr[i]);
        int re = __builtin_amdgcn_readfirstlane(row_ptr[i + 1]);
        float dq = 0.f;
        v2f dm01 = (v2f){0.f, 0.f};
        float dm2 = 0.f;

        f16x8 a = load_phi_frag(geom, rs, c0, quad, E);
        for (int ts = rs; ts < re; ts += 16) {
#pragma unroll
            for (int jj = 0; jj < NT; jj++) {
                int jx = NT * w + jj;
                f32x4 acc = (f32x4){0.f, 0.f, 0.f, 0.f};
                acc = __builtin_amdgcn_mfma_f32_16x16x32_f16(a, Bf[jj], acc, 0, 0, 0);
#pragma unroll
                for (int r = 0; r < 4; r++)
                    Ws[(quad * 4 + r) * WS + 16 * jx + c0] = f16_bits(acc[r]);
            }
            __syncthreads();
            if (ts + 16 < re) a = load_phi_frag(geom, ts + 16, c0, quad, E);

            int te = (re < ts + 16) ? re : ts + 16;
            for (int e = ts + sub; e < te; e += 2) {
                int j = __builtin_amdgcn_readfirstlane(idx_j[e]);
                const unsigned int* Pj = P + (size_t)j * 384;
                unsigned int A = Pj[f];
                unsigned int B = 0, C = 0;
                if (HAS_MU) { B = Pj[128 + f]; C = Pj[256 + f]; }

                const float* g = (const float*)(geom + (size_t)e * 16);
                float dirx = g[0], diry = g[1], dirz = g[2];

                int eloc = e - ts;
                float wq = f16_to_f(Ws[eloc * WS + f]);
                float wr = f16_to_f(Ws[eloc * WS + 128 + f]);

                float xq = unpk_lo(A), xr = unpk_hi(A);
                dq += wq * xq;
                float s_r = wr * xr;
                if (HAS_MU) {
                    float wm = f16_to_f(Ws[eloc * WS + 256 + f]);
                    float xm = unpk_lo(C);
                    float s_m = wm * xm;
                    dm01 += (v2f){s_r, s_r} * (v2f){dirx, diry} +
                            (v2f){s_m, s_m} * (v2f){unpk_lo(B), unpk_hi(B)};
                    dm2  += s_r * dirz + s_m * unpk_hi(C);
                } else {
                    dm01 += (v2f){s_r, s_r} * (v2f){dirx, diry};
                    dm2  += s_r * dirz;
                }
            }
            __syncthreads();
        }

        if (sub == 1) { red[0][f] = dq; red[1][f] = dm01.x; red[2][f] = dm01.y; red[3][f] = dm2; }
        __syncthreads();
        if (sub == 0) {
            dq += red[0][f];
            float d0 = dm01.x + red[1][f], d1 = dm01.y + red[2][f];
            dm2 += red[3][f];
            q[(size_t)i * 128 + f] += dq;
            size_t base = (size_t)i * 384;
            if (HAS_MU) {
                muD[base + f]       += d0;
                muD[base + 128 + f] += d1;
                muD[base + 256 + f] += dm2;
            } else {   // layer 0: mu starts at zero
                muD[base + f]       = d0;
                muD[base + 128 + f] = d1;
                muD[base + 256 + f] = dm2;
            }
        }
        __syncthreads();
    }
}

// ---------------------------------------------------------------------------
// Fused mixing(l) + node-message(l+1) — 512 THREADS (8 waves per 16-node
// tile). Rationale: 625 blocks at 3/CU are ALL co-resident (single round),
// so dispatch time ~= per-block serial chain; the chain is barrier-locked
// (all waves at the same phase -> no cross-wave overlap), so the lever is
// halving per-WAVE work: each wave now owns 1 mux V-tile / 1 W1 tile /
// 3 W2 tiles / 1 niW1 / 3 niW2 (half of before). LDS unchanged (54144 B).
__global__ __launch_bounds__(512, 4) void k_mix_fused(
        float* __restrict__ q, float* __restrict__ mu,
        const unsigned short* __restrict__ muxWt,   // [256][128] bf16 (c,k)
        const unsigned short* __restrict__ W1t,     // [128][256]
        const unsigned short* __restrict__ W2t,     // [384][128]
        const float* __restrict__ b1,
        const float* __restrict__ b2,
        const unsigned short* __restrict__ niW1t,   // next-layer node W1t
        const float* __restrict__ nib1,
        const unsigned short* __restrict__ niW2t,   // next-layer node W2t
        const float* __restrict__ nib2,
        int has_node,
        unsigned int* __restrict__ P, int N) {
    constexpr int XS = 516;                         // f32 row stride; S at +388
    __shared__ __align__(16) unsigned char LDSm[54144];
    unsigned short* A   = (unsigned short*)LDSm;             // [16][264] bf16
    unsigned short* Wsp = (unsigned short*)(LDSm + 8448);    // [3][16][132] bf16
    float*          Xs  = (float*)(LDSm + 21120);            // [16][516] f32
    unsigned short* Amu = (unsigned short*)(LDSm + 21120);   // [48][136] (aliases Xs)

    int t = threadIdx.x;
    int w = t >> 6, l = t & 63, quad = l >> 4, c0 = l & 15;
    int n0 = blockIdx.x * 16;

    // ---- single staging phase: q -> A[:, 0..128), mu -> Amu[48][128] ----
#pragma unroll
    for (int i = 0; i < 2; i++) {
        int flat = i * 512 + t;
        int node = flat >> 6, cp = flat & 63, gn = n0 + node;
        unsigned int v = 0u;
        if (gn < N) { const float* s = q + (size_t)gn * 128 + 2 * cp; v = pack_bf2(s[0], s[1]); }
        *(unsigned int*)&A[node * 264 + 2 * cp] = v;
    }
#pragma unroll
    for (int i = 0; i < 6; i++) {
        int flat = i * 512 + t;
        int row = flat >> 6, cp = flat & 63;
        int node = row & 15, c = row >> 4, gn = n0 + node;
        unsigned int v = 0u;
        if (gn < N) {
            const float* s = mu + (size_t)gn * 384 + c * 128 + 2 * cp;
            v = pack_bf2(s[0], s[1]);
        }
        *(unsigned int*)&Amu[row * 136 + 2 * cp] = v;
    }
    __syncthreads();                                              // B1

    // ---- one-shot mu_mix: wave w owns V-tile jv=w and W-tile jv+8 ----
    f32x4 vn2 = (f32x4){0, 0, 0, 0}, S = (f32x4){0, 0, 0, 0};
#pragma unroll
    for (int rt = 0; rt < 3; rt++) {
        bf16x8 af[4];
#pragma unroll
        for (int ks = 0; ks < 4; ks++)
            af[ks] = *(const bf16x8*)&Amu[(rt * 16 + c0) * 136 + ks * 32 + quad * 8];
        f32x4 V = (f32x4){0, 0, 0, 0}, Wm = (f32x4){0, 0, 0, 0};
#pragma unroll
        for (int ks = 0; ks < 4; ks++) {
            bf16x8 bV = *(const bf16x8*)&muxWt[(16 * w + c0) * 128 + ks * 32 + quad * 8];
            V = __builtin_amdgcn_mfma_f32_16x16x32_bf16(af[ks], bV, V, 0, 0, 0);
        }
#pragma unroll
        for (int ks = 0; ks < 4; ks++) {
            bf16x8 bW = *(const bf16x8*)&muxWt[(16 * (w + 8) + c0) * 128 + ks * 32 + quad * 8];
            Wm = __builtin_amdgcn_mfma_f32_16x16x32_bf16(af[ks], bW, Wm, 0, 0, 0);
        }
        vn2 += V * V;
        S   += V * Wm;
#pragma unroll
        for (int r = 0; r < 4; r++)
            Wsp[rt * 2112 + (quad * 4 + r) * 132 + 16 * w + c0] =
                (unsigned short)bf16_rtne(Wm[r]);
    }
    // mu_Vn -> A[:, 128..256) (ctx second half)
#pragma unroll
    for (int r = 0; r < 4; r++)
        A[(quad * 4 + r) * 264 + 128 + 16 * w + c0] =
            (unsigned short)bf16_rtne(sqrtf(vn2[r] + 1e-8f));
    __syncthreads();                                              // B2

    bf16x8 a2[8];
#pragma unroll
    for (int ks = 0; ks < 8; ks++)
        a2[ks] = *(const bf16x8*)&A[c0 * 264 + ks * 32 + quad * 8];
    {
        unsigned short htmp[4];
        float bb = b1[16 * w + c0];
        f32x4 acc = (f32x4){bb, bb, bb, bb};
#pragma unroll
        for (int ks = 0; ks < 8; ks++) {
            bf16x8 b = *(const bf16x8*)&W1t[(16 * w + c0) * 256 + ks * 32 + quad * 8];
            acc = __builtin_amdgcn_mfma_f32_16x16x32_bf16(a2[ks], b, acc, 0, 0, 0);
        }
#pragma unroll
        for (int r = 0; r < 4; r++) {
            float aa = acc[r];
            htmp[r] = (unsigned short)bf16_rtne(aa / (1.f + __expf(-aa)));
        }
        __syncthreads();                                          // B3 (WAR vs a2)
#pragma unroll
        for (int r = 0; r < 4; r++)
            A[(quad * 4 + r) * 264 + 128 + 16 * w + c0] = htmp[r];
    }
    __syncthreads();                                              // B4

    bf16x8 a3[4];
#pragma unroll
    for (int ks = 0; ks < 4; ks++)
        a3[ks] = *(const bf16x8*)&A[c0 * 264 + 128 + ks * 32 + quad * 8];
#pragma unroll
    for (int jj = 0; jj < 3; jj++) {
        int jx = 3 * w + jj;
        float bb = b2[16 * jx + c0];
        f32x4 acc = (f32x4){bb, bb, bb, bb};
#pragma unroll
        for (int ks = 0; ks < 4; ks++) {
            bf16x8 b = *(const bf16x8*)&W2t[(16 * jx + c0) * 128 + ks * 32 + quad * 8];
            acc = __builtin_amdgcn_mfma_f32_16x16x32_bf16(a3[ks], b, acc, 0, 0, 0);
        }
#pragma unroll
        for (int r = 0; r < 4; r++)
            Xs[(quad * 4 + r) * XS + 16 * jx + c0] = acc[r];
    }
#pragma unroll
    for (int r = 0; r < 4; r++)
        Xs[(quad * 4 + r) * XS + 388 + 16 * w + c0] = S[r];
    __syncthreads();                                              // B5

    int n = t >> 4, fi = (t & 15) * 8;
    int gn = n0 + n;
    if (t < 256 && gn < N) {
        float* qp = q + (size_t)gn * 128 + fi;
        float qn[8];
#pragma unroll
        for (int k = 0; k < 8; k++) {
            qn[k] = qp[k] + Xs[n * XS + fi + k] +
                    Xs[n * XS + 256 + fi + k] * Xs[n * XS + 388 + fi + k];
            qp[k] = qn[k];
        }
        unsigned int qd[4];
#pragma unroll
        for (int p = 0; p < 4; p++) qd[p] = pack_bf2(qn[2 * p], qn[2 * p + 1]);
        *(uint4*)&A[n * 264 + fi] = make_uint4(qd[0], qd[1], qd[2], qd[3]);

        size_t base = (size_t)gn * 384;
        float m[3][8];
#pragma unroll
        for (int c = 0; c < 3; c++) {
            float* mp = mu + base + c * 128 + fi;
#pragma unroll
            for (int k = 0; k < 8; k++) {
                m[c][k] = mp[k] + Xs[n * XS + 128 + fi + k] *
                                  bf16_to_f(Wsp[c * 2112 + n * 132 + fi + k]);
                mp[k] = m[c][k];
            }
        }
        if (has_node) {   // P mu-rows only consumed by the next edge layer
            unsigned int d[8];
#pragma unroll
            for (int k = 0; k < 8; k++) {
                d[k] = pack_bf2(m[0][k], m[1][k]);
                ((unsigned short*)&P[base + 256 + fi + k])[1] = (unsigned short)bf16_rtne(m[2][k]);
            }
            *(uint4*)&P[base + 128 + fi]     = make_uint4(d[0], d[1], d[2], d[3]);
            *(uint4*)&P[base + 128 + fi + 4] = make_uint4(d[4], d[5], d[6], d[7]);
        }
    }
    __syncthreads();                                              // B6

    if (has_node) {
        unsigned short* Ah = Wsp;   // reuse (Wsp reads finished at B6)
        bf16x8 a1[4];
#pragma unroll
        for (int ks = 0; ks < 4; ks++)
            a1[ks] = *(const bf16x8*)&A[c0 * 264 + ks * 32 + quad * 8];
        {
            float bb = nib1[16 * w + c0];
            f32x4 acc = (f32x4){bb, bb, bb, bb};
#pragma unroll
            for (int ks = 0; ks < 4; ks++) {
                bf16x8 b = *(const bf16x8*)&niW1t[(16 * w + c0) * 128 + ks * 32 + quad * 8];
                acc = __builtin_amdgcn_mfma_f32_16x16x32_bf16(a1[ks], b, acc, 0, 0, 0);
            }
#pragma unroll
            for (int r = 0; r < 4; r++) {
                float aa = acc[r];
                Ah[(quad * 4 + r) * 136 + 16 * w + c0] =
                    (unsigned short)bf16_rtne(aa / (1.f + __expf(-aa)));
            }
        }
        __syncthreads();                                          // B7

        bf16x8 a4[4];
#pragma unroll
        for (int ks = 0; ks < 4; ks++)
            a4[ks] = *(const bf16x8*)&Ah[c0 * 136 + ks * 32 + quad * 8];
#pragma unroll
        for (int jj = 0; jj < 3; jj++) {
            int jx = 3 * w + jj;
            float bb = nib2[16 * jx + c0];
            f32x4 acc = (f32x4){bb, bb, bb, bb};
#pragma unroll
            for (int ks = 0; ks < 4; ks++) {
                bf16x8 b = *(const bf16x8*)&niW2t[(16 * jx + c0) * 128 + ks * 32 + quad * 8];
                acc = __builtin_amdgcn_mfma_f32_16x16x32_bf16(a4[ks], b, acc, 0, 0, 0);
            }
#pragma unroll
            for (int r = 0; r < 4; r++)
                Xs[(quad * 4 + r) * XS + 16 * jx + c0] = acc[r];
        }
        __syncthreads();                                          // B8

        if (t < 256 && gn < N) {
            size_t base = (size_t)gn * 384;
            unsigned int d[8];
#pragma unroll
            for (int k = 0; k < 8; k++) {
                float x0 = Xs[n * XS + fi + k];
                float x1 = Xs[n * XS + 128 + fi + k];
                float x2 = Xs[n * XS + 256 + fi + k];
                d[k] = pack_bf2(x0, x1);
                ((unsigned short*)&P[base + 256 + fi + k])[0] = (unsigned short)bf16_rtne(x2);
            }
            *(uint4*)&P[base + fi]     = make_uint4(d[0], d[1], d[2], d[3]);
            *(uint4*)&P[base + fi + 4] = make_uint4(d[4], d[5], d[6], d[7]);
        }
    }
}

// ---------------------------------------------------------------------------
extern "C" void kernel_launch(void* const* d_in, const int* in_sizes, int n_in,
                              void* d_out, int out_size, void* d_ws, size_t ws_size,
                              hipStream_t stream) {
    const int*   Z      = (const int*)d_in[0];
    const float* r_ij   = (const float*)d_in[1];
    const int*   idx_i  = (const int*)d_in[2];
    const int*   idx_j  = (const int*)d_in[3];
    const float* emb    = (const float*)d_in[4];
    const float* filt_W = (const float*)d_in[5];
    const float* filt_b = (const float*)d_in[6];
    const float* int_W1 = (const float*)d_in[7];
    const float* int_b1 = (const float*)d_in[8];
    const float* int_W2 = (const float*)d_in[9];
    const float* int_b2 = (const float*)d_in[10];
    const float* mix_W1 = (const float*)d_in[11];
    const float* mix_b1 = (const float*)d_in[12];
    const float* mix_W2 = (const float*)d_in[13];
    const float* mix_b2 = (const float*)d_in[14];
    const float* mux_W  = (const float*)d_in[15];

    int N = in_sizes[0];
    int E = in_sizes[2];

    float* q   = (float*)d_out;              // [N,128]  q state (fp32)
    float* muD = q + (size_t)N * 128;        // [N,3,128] mu state (fp32)

    unsigned int* geom = (unsigned int*)d_ws;                 // E*16 u32 (64 B/edge)
    unsigned int* P = geom + (size_t)E * 16;                  // N*384 u32
    int* row_ptr = (int*)(P + (size_t)N * 384);               // N+1
    uintptr_t waddr = (uintptr_t)(row_ptr + N + 1);
    waddr = (waddr + 15) & ~(uintptr_t)15;
    unsigned short* muxWt = (unsigned short*)waddr;   // 3*256*128
    unsigned short* W1t   = muxWt + 98304;            // 3*128*256
    unsigned short* W2t   = W1t + 98304;              // 3*384*128
    unsigned short* iW1t  = W2t + 147456;             // 3*128*128
    unsigned short* iW2t  = iW1t + 49152;             // 3*384*128
    unsigned short* filtWt = iW2t + 147456;           // 3*384*24 f16

    int nbR = (N + 1 + 255) / 256;
    int nbG = (E + 255) / 256;
    k_pre<<<nbR + nbG + 2220, 256, 0, stream>>>(
        idx_i, row_ptr, r_ij, geom,
        mux_W, mix_W1, mix_W2, int_W1, int_W2, filt_W, filt_b,
        muxWt, W1t, W2t, iW1t, iW2t, filtWt, N, E, nbR, nbG);

    int tiles = (N + 15) / 16;
    k_node_mfma<<<tiles, 256, 0, stream>>>(
        Z, emb, q, iW1t, int_b1, iW2t, int_b2, P, N);
    for (int l = 0; l < 3; l++) {
        if (l == 0)
            k_edge<false><<<(N + NPB - 1) / NPB, 256, 0, stream>>>(
                P, geom, idx_j, row_ptr, filtWt, q, muD, N, E);
        else
            k_edge<true><<<(N + NPB - 1) / NPB, 256, 0, stream>>>(
                P, geom, idx_j, row_ptr, filtWt + (size_t)l * 9216, q, muD, N, E);
        int nl = (l < 2) ? (l + 1) : 0;
        k_mix_fused<<<tiles, 512, 0, stream>>>(
            q, muD, muxWt + (size_t)l * 32768, W1t + (size_t)l * 32768,
            W2t + (size_t)l * 49152, mix_b1 + l * 128, mix_b2 + l * 384,
            iW1t + (size_t)nl * 16384, int_b1 + nl * 128,
            iW2t + (size_t)nl * 49152, int_b2 + nl * 384,
            (l < 2) ? 1 : 0, P, N);
    }
    // q in d_out; final mu (fp32 state) in muD = d_out mu region.
}

// Round 10
// 492.440 us; speedup vs baseline: 1.7883x; 1.0188x over previous
//
#include <hip/hip_runtime.h>
#include <hip/hip_bf16.h>
#include <hip/hip_fp16.h>

#define F_DIM 128
#define N_RBF 20
#define CUTOFF 5.0f
#define PI_F 3.14159265358979323846f
#define NPB 4   // nodes per k_edge block

typedef float v2f __attribute__((ext_vector_type(2)));
typedef __attribute__((ext_vector_type(8))) short bf16x8;
typedef __attribute__((ext_vector_type(4))) float f32x4;
typedef _Float16 h2f __attribute__((ext_vector_type(2)));
typedef _Float16 f16x8 __attribute__((ext_vector_type(8)));

__device__ __forceinline__ unsigned int bf16_rtne(float f) {
    unsigned int u = __float_as_uint(f);
    u += 0x7fffu + ((u >> 16) & 1u);
    return u >> 16;
}
__device__ __forceinline__ unsigned int pack_bf2(float lo, float hi) {
    return bf16_rtne(lo) | (bf16_rtne(hi) << 16);
}
__device__ __forceinline__ float unpk_lo(unsigned int u) {
    return __uint_as_float(u << 16);
}
__device__ __forceinline__ float unpk_hi(unsigned int u) {
    return __uint_as_float(u & 0xffff0000u);
}
__device__ __forceinline__ float bf16_to_f(unsigned short s) {
    return __uint_as_float(((unsigned int)s) << 16);
}
__device__ __forceinline__ unsigned int pack_h2(float lo, float hi) {
    h2f h = (h2f){(_Float16)lo, (_Float16)hi};
    return __builtin_bit_cast(unsigned int, h);
}
__device__ __forceinline__ unsigned short f16_bits(float f) {
    _Float16 h = (_Float16)f;
    return __builtin_bit_cast(unsigned short, h);
}
__device__ __forceinline__ float f16_to_f(unsigned short s) {
    return (float)__builtin_bit_cast(_Float16, s);
}

// Payload layout (request-count experiment, R9->R10):
//   PA  = P                : [N][128] u32, (xq|xr) bf16 pairs
//   PBC = P + N*128        : [N][128] uint2, .x=(mu0|mu1), .y=(xm lo|mu2 hi)
// Edge gather: A = 1 dword load; B,C = ONE dwordx2 load (was 2 dwords).
// Bytes and cache footprint identical to the old [N][384] layout — only the
// per-lane request count changes (3 -> 2). Discriminates request-throughput
// vs line-bandwidth bound.

// ---------------------------------------------------------------------------
// Merged preprocessing: [0,nbR) rowptr | [nbR,nbR+nbG) geom | rest: weight prep.
__global__ __launch_bounds__(256) void k_pre(
        const int* __restrict__ idx_i, int* __restrict__ row_ptr,
        const float* __restrict__ r, unsigned int* __restrict__ geom,
        const float* __restrict__ muxW,
        const float* __restrict__ W1,
        const float* __restrict__ W2,
        const float* __restrict__ iW1,
        const float* __restrict__ iW2,
        const float* __restrict__ filt_W,
        const float* __restrict__ filt_b,
        unsigned short* __restrict__ muxWt,
        unsigned short* __restrict__ W1t,
        unsigned short* __restrict__ W2t,
        unsigned short* __restrict__ iW1t,
        unsigned short* __restrict__ iW2t,
        unsigned short* __restrict__ filtWt,
        int N, int E, int nbR, int nbG) {
    int bid = blockIdx.x;
    if (bid < nbR) {
        // ---- row_ptr via binary search ----
        int i = bid * 256 + threadIdx.x;
        if (i > N) return;
        if (i == N) { row_ptr[N] = E; return; }
        int lo = 0, hi = E;
        while (lo < hi) {
            int mid = (lo + hi) >> 1;
            if (idx_i[mid] < i) lo = mid + 1; else hi = mid;
        }
        row_ptr[i] = lo;
        return;
    }
    if (bid < nbR + nbG) {
        // ---- geometry record: 16 dwords/edge ----
        int e = (bid - nbR) * 256 + threadIdx.x;
        if (e >= E) return;
        float x = r[e * 3], y = r[e * 3 + 1], z = r[e * 3 + 2];
        float d = sqrtf(x * x + y * y + z * z);
        float inv = 1.f / d;
        float fc = (d < CUTOFF) ? 0.5f * (__cosf(d * (PI_F / CUTOFF)) + 1.f) : 0.f;
        unsigned int* g = geom + (size_t)e * 16;
        float dx = x * inv, dy = y * inv, dz = z * inv;
        g[0] = __float_as_uint(dx);
        g[1] = __float_as_uint(dy);
        g[2] = __float_as_uint(dz);
        g[3] = __float_as_uint(fc);
        const float delta = CUTOFF / (N_RBF - 1);
        const float coeff = -0.5f / (delta * delta);
        float ph[N_RBF];
#pragma unroll
        for (int k = 0; k < N_RBF; k++) {
            float t = d - k * delta;
            ph[k] = __expf(coeff * t * t) * fc;
        }
#pragma unroll
        for (int k = 0; k < N_RBF / 2; k++)
            g[4 + k] = pack_h2(ph[2 * k], ph[2 * k + 1]);
        g[14] = pack_h2(fc, dx);
        g[15] = pack_h2(dy, dz);
        return;
    }
    // ---- weight prep ----
    int idx = (bid - nbR - nbG) * 256 + threadIdx.x;
    if (idx < 98304) {                     // muxWt[l][c<256][k<128]
        int l = idx / 32768, rem = idx % 32768;
        int c = rem / 128, k = rem % 128;
        muxWt[idx] = (unsigned short)bf16_rtne(muxW[l * 32768 + k * 256 + c]);
    } else if (idx < 196608) {             // W1t[l][c<128][k<256]
        int i2 = idx - 98304;
        int l = i2 / 32768, rem = i2 % 32768;
        int c = rem / 256, k = rem % 256;
        W1t[i2] = (unsigned short)bf16_rtne(W1[l * 32768 + k * 128 + c]);
    } else if (idx < 344064) {             // W2t[l][c<384][k<128]
        int i2 = idx - 196608;
        int l = i2 / 49152, rem = i2 % 49152;
        int c = rem / 128, k = rem % 128;
        W2t[i2] = (unsigned short)bf16_rtne(W2[l * 49152 + k * 384 + c]);
    } else if (idx < 393216) {             // iW1t[l][c<128][k<128]
        int i2 = idx - 344064;
        int l = i2 / 16384, rem = i2 % 16384;
        int c = rem / 128, k = rem % 128;
        iW1t[i2] = (unsigned short)bf16_rtne(iW1[l * 16384 + k * 128 + c]);
    } else if (idx < 540672) {             // iW2t[l][c<384][k<128]
        int i2 = idx - 393216;
        int l = i2 / 49152, rem = i2 % 49152;
        int c = rem / 128, k = rem % 128;
        iW2t[i2] = (unsigned short)bf16_rtne(iW2[l * 49152 + k * 384 + c]);
    } else if (idx < 568320) {             // filtWt[l][c<384][k<24] f16
        int i2 = idx - 540672;
        int l = i2 / 9216, rem = i2 % 9216;
        int c = rem / 24, k = rem % 24;
        float v = 0.f;
        if (k < 20)       v = filt_W[k * 1152 + l * 384 + c];
        else if (k == 20) v = filt_b[l * 384 + c];
        _Float16 hv = (_Float16)v;
        filtWt[i2] = __builtin_bit_cast(unsigned short, hv);
    }
}

// ---------------------------------------------------------------------------
// Node message MLP via MFMA (layer 0 only), q-init fused. Writes ONLY the
// PA table: layer-0's x2 (dmumu channel) was dead — mu=0 at l0 so edge<false>
// never reads it, and mix0 rewrites layer-1's x fully. Also skips the 8 W2
// tiles that produced x2.
__global__ __launch_bounds__(256) void k_node_mfma(
        const int* __restrict__ Z,
        const float* __restrict__ emb,
        float* __restrict__ q,
        const unsigned short* __restrict__ iW1t,   // [128][128] bf16 (c,k)
        const float* __restrict__ b1,
        const unsigned short* __restrict__ iW2t,   // [384][128]
        const float* __restrict__ b2,
        unsigned int* __restrict__ P, int N) {
    __shared__ unsigned short A[16 * 136];
    __shared__ unsigned short Ah[16 * 136];
    __shared__ float Xs[16 * 396];
    int t = threadIdx.x;
    int w = t >> 6, l = t & 63, quad = l >> 4, c0 = l & 15;
    int n0 = blockIdx.x * 16;

#pragma unroll
    for (int i = 0; i < 4; i++) {
        int flat = i * 256 + t;
        int node = flat >> 6, cp = flat & 63;
        int gn = n0 + node;
        unsigned int v = 0u;
        if (gn < N) {
            const float* s = emb + (size_t)Z[gn] * 128 + 2 * cp;
            float s0 = s[0], s1 = s[1];
            v = pack_bf2(s0, s1);
            float* qo = q + (size_t)gn * 128 + 2 * cp;
            qo[0] = s0; qo[1] = s1;
        }
        *(unsigned int*)&A[node * 136 + 2 * cp] = v;
    }
    __syncthreads();

    bf16x8 a1[4];
#pragma unroll
    for (int ks = 0; ks < 4; ks++)
        a1[ks] = *(const bf16x8*)&A[c0 * 136 + ks * 32 + quad * 8];
#pragma unroll
    for (int jj = 0; jj < 2; jj++) {
        int jg = 2 * w + jj;
        float bb = b1[16 * jg + c0];
        f32x4 acc = (f32x4){bb, bb, bb, bb};
#pragma unroll
        for (int ks = 0; ks < 4; ks++) {
            bf16x8 b = *(const bf16x8*)&iW1t[(16 * jg + c0) * 128 + ks * 32 + quad * 8];
            acc = __builtin_amdgcn_mfma_f32_16x16x32_bf16(a1[ks], b, acc, 0, 0, 0);
        }
#pragma unroll
        for (int r = 0; r < 4; r++) {
            float aa = acc[r];
            Ah[(quad * 4 + r) * 136 + 16 * jg + c0] =
                (unsigned short)bf16_rtne(aa / (1.f + __expf(-aa)));
        }
    }
    __syncthreads();

    bf16x8 a3[4];
#pragma unroll
    for (int ks = 0; ks < 4; ks++)
        a3[ks] = *(const bf16x8*)&Ah[c0 * 136 + ks * 32 + quad * 8];
#pragma unroll
    for (int jj = 0; jj < 4; jj++) {       // only x0,x1 cols (0..255); x2 dead at l0
        int jx = 4 * w + jj;
        float bb = b2[16 * jx + c0];
        f32x4 acc = (f32x4){bb, bb, bb, bb};
#pragma unroll
        for (int ks = 0; ks < 4; ks++) {
            bf16x8 b = *(const bf16x8*)&iW2t[(16 * jx + c0) * 128 + ks * 32 + quad * 8];
            acc = __builtin_amdgcn_mfma_f32_16x16x32_bf16(a3[ks], b, acc, 0, 0, 0);
        }
#pragma unroll
        for (int r = 0; r < 4; r++)
            Xs[(quad * 4 + r) * 396 + 16 * jx + c0] = acc[r];
    }
    __syncthreads();

    int n = t >> 4, fi = (t & 15) * 8;
    int gn = n0 + n;
    if (gn < N) {
        size_t base = (size_t)gn * 128;     // PA row
        unsigned int d[8];
#pragma unroll
        for (int k = 0; k < 8; k++) {
            float x0 = Xs[n * 396 + fi + k];
            float x1 = Xs[n * 396 + 128 + fi + k];
            d[k] = pack_bf2(x0, x1);
        }
        *(uint4*)&P[base + fi]     = make_uint4(d[0], d[1], d[2], d[3]);
        *(uint4*)&P[base + fi + 4] = make_uint4(d[4], d[5], d[6], d[7]);
    }
}

// ---------------------------------------------------------------------------
// A-frag loader for the filter MFMA: 24 f16 channels at geom dwords 4..15,
// K padded to 32 (quad 3 = zeros).
__device__ __forceinline__ f16x8 load_phi_frag(const unsigned int* __restrict__ geom,
                                               int ts, int c0, int quad, int E) {
    int ea = ts + c0;
    if (ea >= E) ea = E - 1;          // clamp; pad rows are never aggregated
    f16x8 a = {};
    if (quad < 3)
        a = *(const f16x8*)&geom[(size_t)ea * 16 + 4 + quad * 4];
    return a;
}

// ---------------------------------------------------------------------------
// Edge aggregation (R5/R8 structure). Gather now 2 requests/lane/edge
// (A dword + BC dwordx2) instead of 3 — bytes unchanged.
template <bool HAS_MU>
__global__ __launch_bounds__(256, 8) void k_edge(
        const unsigned int* __restrict__ P,
        const unsigned int* __restrict__ geom,
        const int* __restrict__ idx_j,
        const int* __restrict__ row_ptr,
        const unsigned short* __restrict__ filtWt,  // [384][24] f16 (layer slice)
        float* __restrict__ q,
        float* __restrict__ muD, int N, int E) {
    constexpr int NT = HAS_MU ? 6 : 4;     // 16-col tiles per wave (24 or 16 total)
    constexpr int WS = HAS_MU ? 412 : 268; // ushort row stride
    __shared__ unsigned short Ws[16 * WS];
    __shared__ float red[4][128];
    int t = threadIdx.x;
    int f = t & 127;
    int sub = __builtin_amdgcn_readfirstlane(t >> 7);
    int w = t >> 6, l = t & 63, quad = l >> 4, c0 = l & 15;
    const unsigned int* PA = P;
    const unsigned int* PBC = P + (size_t)N * 128;

    f16x8 Bf[NT];
#pragma unroll
    for (int jj = 0; jj < NT; jj++) {
        int jx = NT * w + jj;
        f16x8 b = {};
        if (quad < 3)
            b = *(const f16x8*)&filtWt[(16 * jx + c0) * 24 + quad * 8];
        Bf[jj] = b;
    }

    int i0 = blockIdx.x * NPB;
    for (int nn = 0; nn < NPB; nn++) {
        int i = i0 + nn;
        if (i >= N) break;
        int rs = __builtin_amdgcn_readfirstlane(row_ptr[i]);
        int re = __builtin_amdgcn_readfirstlane(row_ptr[i + 1]);
        float dq = 0.f;
        v2f dm01 = (v2f){0.f, 0.f};
        float dm2 = 0.f;

        f16x8 a = load_phi_frag(geom, rs, c0, quad, E);
        for (int ts = rs; ts < re; ts += 16) {
#pragma unroll
            for (int jj = 0; jj < NT; jj++) {
                int jx = NT * w + jj;
                f32x4 acc = (f32x4){0.f, 0.f, 0.f, 0.f};
                acc = __builtin_amdgcn_mfma_f32_16x16x32_f16(a, Bf[jj], acc, 0, 0, 0);
#pragma unroll
                for (int r = 0; r < 4; r++)
                    Ws[(quad * 4 + r) * WS + 16 * jx + c0] = f16_bits(acc[r]);
            }
            __syncthreads();
            if (ts + 16 < re) a = load_phi_frag(geom, ts + 16, c0, quad, E);

            int te = (re < ts + 16) ? re : ts + 16;
            for (int e = ts + sub; e < te; e += 2) {
                int j = __builtin_amdgcn_readfirstlane(idx_j[e]);
                unsigned int A = PA[(size_t)j * 128 + f];
                unsigned int B = 0, C = 0;
                if (HAS_MU) {
                    uint2 bc = *(const uint2*)&PBC[(size_t)j * 256 + 2 * f];
                    B = bc.x; C = bc.y;
                }

                const float* g = (const float*)(geom + (size_t)e * 16);
                float dirx = g[0], diry = g[1], dirz = g[2];

                int eloc = e - ts;
                float wq = f16_to_f(Ws[eloc * WS + f]);
                float wr = f16_to_f(Ws[eloc * WS + 128 + f]);

                float xq = unpk_lo(A), xr = unpk_hi(A);
                dq += wq * xq;
                float s_r = wr * xr;
                if (HAS_MU) {
                    float wm = f16_to_f(Ws[eloc * WS + 256 + f]);
                    float xm = unpk_lo(C);
                    float s_m = wm * xm;
                    dm01 += (v2f){s_r, s_r} * (v2f){dirx, diry} +
                            (v2f){s_m, s_m} * (v2f){unpk_lo(B), unpk_hi(B)};
                    dm2  += s_r * dirz + s_m * unpk_hi(C);
                } else {
                    dm01 += (v2f){s_r, s_r} * (v2f){dirx, diry};
                    dm2  += s_r * dirz;
                }
            }
            __syncthreads();
        }

        if (sub == 1) { red[0][f] = dq; red[1][f] = dm01.x; red[2][f] = dm01.y; red[3][f] = dm2; }
        __syncthreads();
        if (sub == 0) {
            dq += red[0][f];
            float d0 = dm01.x + red[1][f], d1 = dm01.y + red[2][f];
            dm2 += red[3][f];
            q[(size_t)i * 128 + f] += dq;
            size_t base = (size_t)i * 384;
            if (HAS_MU) {
                muD[base + f]       += d0;
                muD[base + 128 + f] += d1;
                muD[base + 256 + f] += dm2;
            } else {   // layer 0: mu starts at zero
                muD[base + f]       = d0;
                muD[base + 128 + f] = d1;
                muD[base + 256 + f] = dm2;
            }
        }
        __syncthreads();
    }
}

// ---------------------------------------------------------------------------
// Fused mixing(l) + node-message(l+1) — 512 threads / 8 waves (R9 win).
// P writes moved entirely to the has_node epilogue as packed uint4 stores
// to PA + PBC (new layout); mu bf16 kept in registers across B7/B8.
__global__ __launch_bounds__(512, 4) void k_mix_fused(
        float* __restrict__ q, float* __restrict__ mu,
        const unsigned short* __restrict__ muxWt,   // [256][128] bf16 (c,k)
        const unsigned short* __restrict__ W1t,     // [128][256]
        const unsigned short* __restrict__ W2t,     // [384][128]
        const float* __restrict__ b1,
        const float* __restrict__ b2,
        const unsigned short* __restrict__ niW1t,   // next-layer node W1t
        const float* __restrict__ nib1,
        const unsigned short* __restrict__ niW2t,   // next-layer node W2t
        const float* __restrict__ nib2,
        int has_node,
        unsigned int* __restrict__ P, int N) {
    constexpr int XS = 516;                         // f32 row stride; S at +388
    __shared__ __align__(16) unsigned char LDSm[54144];
    unsigned short* A   = (unsigned short*)LDSm;             // [16][264] bf16
    unsigned short* Wsp = (unsigned short*)(LDSm + 8448);    // [3][16][132] bf16
    float*          Xs  = (float*)(LDSm + 21120);            // [16][516] f32
    unsigned short* Amu = (unsigned short*)(LDSm + 21120);   // [48][136] (aliases Xs)

    int t = threadIdx.x;
    int w = t >> 6, l = t & 63, quad = l >> 4, c0 = l & 15;
    int n0 = blockIdx.x * 16;
    unsigned int* PA = P;
    unsigned int* PBC = P + (size_t)N * 128;

    // ---- single staging phase: q -> A[:, 0..128), mu -> Amu[48][128] ----
#pragma unroll
    for (int i = 0; i < 2; i++) {
        int flat = i * 512 + t;
        int node = flat >> 6, cp = flat & 63, gn = n0 + node;
        unsigned int v = 0u;
        if (gn < N) { const float* s = q + (size_t)gn * 128 + 2 * cp; v = pack_bf2(s[0], s[1]); }
        *(unsigned int*)&A[node * 264 + 2 * cp] = v;
    }
#pragma unroll
    for (int i = 0; i < 6; i++) {
        int flat = i * 512 + t;
        int row = flat >> 6, cp = flat & 63;
        int node = row & 15, c = row >> 4, gn = n0 + node;
        unsigned int v = 0u;
        if (gn < N) {
            const float* s = mu + (size_t)gn * 384 + c * 128 + 2 * cp;
            v = pack_bf2(s[0], s[1]);
        }
        *(unsigned int*)&Amu[row * 136 + 2 * cp] = v;
    }
    __syncthreads();                                              // B1

    // ---- one-shot mu_mix: wave w owns V-tile jv=w and W-tile jv+8 ----
    f32x4 vn2 = (f32x4){0, 0, 0, 0}, S = (f32x4){0, 0, 0, 0};
#pragma unroll
    for (int rt = 0; rt < 3; rt++) {
        bf16x8 af[4];
#pragma unroll
        for (int ks = 0; ks < 4; ks++)
            af[ks] = *(const bf16x8*)&Amu[(rt * 16 + c0) * 136 + ks * 32 + quad * 8];
        f32x4 V = (f32x4){0, 0, 0, 0}, Wm = (f32x4){0, 0, 0, 0};
#pragma unroll
        for (int ks = 0; ks < 4; ks++) {
            bf16x8 bV = *(const bf16x8*)&muxWt[(16 * w + c0) * 128 + ks * 32 + quad * 8];
            V = __builtin_amdgcn_mfma_f32_16x16x32_bf16(af[ks], bV, V, 0, 0, 0);
        }
#pragma unroll
        for (int ks = 0; ks < 4; ks++) {
            bf16x8 bW = *(const bf16x8*)&muxWt[(16 * (w + 8) + c0) * 128 + ks * 32 + quad * 8];
            Wm = __builtin_amdgcn_mfma_f32_16x16x32_bf16(af[ks], bW, Wm, 0, 0, 0);
        }
        vn2 += V * V;
        S   += V * Wm;
#pragma unroll
        for (int r = 0; r < 4; r++)
            Wsp[rt * 2112 + (quad * 4 + r) * 132 + 16 * w + c0] =
                (unsigned short)bf16_rtne(Wm[r]);
    }
    // mu_Vn -> A[:, 128..256) (ctx second half)
#pragma unroll
    for (int r = 0; r < 4; r++)
        A[(quad * 4 + r) * 264 + 128 + 16 * w + c0] =
            (unsigned short)bf16_rtne(sqrtf(vn2[r] + 1e-8f));
    __syncthreads();                                              // B2

    bf16x8 a2[8];
#pragma unroll
    for (int ks = 0; ks < 8; ks++)
        a2[ks] = *(const bf16x8*)&A[c0 * 264 + ks * 32 + quad * 8];
    {
        unsigned short htmp[4];
        float bb = b1[16 * w + c0];
        f32x4 acc = (f32x4){bb, bb, bb, bb};
#pragma unroll
        for (int ks = 0; ks < 8; ks++) {
            bf16x8 b = *(const bf16x8*)&W1t[(16 * w + c0) * 256 + ks * 32 + quad * 8];
            acc = __builtin_amdgcn_mfma_f32_16x16x32_bf16(a2[ks], b, acc, 0, 0, 0);
        }
#pragma unroll
        for (int r = 0; r < 4; r++) {
            float aa = acc[r];
            htmp[r] = (unsigned short)bf16_rtne(aa / (1.f + __expf(-aa)));
        }
        __syncthreads();                                          // B3 (WAR vs a2)
#pragma unroll
        for (int r = 0; r < 4; r++)
            A[(quad * 4 + r) * 264 + 128 + 16 * w + c0] = htmp[r];
    }
    __syncthreads();                                              // B4

    bf16x8 a3[4];
#pragma unroll
    for (int ks = 0; ks < 4; ks++)
        a3[ks] = *(const bf16x8*)&A[c0 * 264 + 128 + ks * 32 + quad * 8];
#pragma unroll
    for (int jj = 0; jj < 3; jj++) {
        int jx = 3 * w + jj;
        float bb = b2[16 * jx + c0];
        f32x4 acc = (f32x4){bb, bb, bb, bb};
#pragma unroll
        for (int ks = 0; ks < 4; ks++) {
            bf16x8 b = *(const bf16x8*)&W2t[(16 * jx + c0) * 128 + ks * 32 + quad * 8];
            acc = __builtin_amdgcn_mfma_f32_16x16x32_bf16(a3[ks], b, acc, 0, 0, 0);
        }
#pragma unroll
        for (int r = 0; r < 4; r++)
            Xs[(quad * 4 + r) * XS + 16 * jx + c0] = acc[r];
    }
#pragma unroll
    for (int r = 0; r < 4; r++)
        Xs[(quad * 4 + r) * XS + 388 + 16 * w + c0] = S[r];
    __syncthreads();                                              // B5

    int n = t >> 4, fi = (t & 15) * 8;
    int gn = n0 + n;
    unsigned int pm01[8];       // pack(mu0,mu1) per k — live into B8
    unsigned int pm2p[4];       // packed bf16(mu2) pairs
    if (t < 256 && gn < N) {
        float* qp = q + (size_t)gn * 128 + fi;
        float qn[8];
#pragma unroll
        for (int k = 0; k < 8; k++) {
            qn[k] = qp[k] + Xs[n * XS + fi + k] +
                    Xs[n * XS + 256 + fi + k] * Xs[n * XS + 388 + fi + k];
            qp[k] = qn[k];
        }
        unsigned int qd[4];
#pragma unroll
        for (int p = 0; p < 4; p++) qd[p] = pack_bf2(qn[2 * p], qn[2 * p + 1]);
        *(uint4*)&A[n * 264 + fi] = make_uint4(qd[0], qd[1], qd[2], qd[3]);

        size_t base = (size_t)gn * 384;
        float m[3][8];
#pragma unroll
        for (int c = 0; c < 3; c++) {
            float* mp = mu + base + c * 128 + fi;
#pragma unroll
            for (int k = 0; k < 8; k++) {
                m[c][k] = mp[k] + Xs[n * XS + 128 + fi + k] *
                                  bf16_to_f(Wsp[c * 2112 + n * 132 + fi + k]);
                mp[k] = m[c][k];
            }
        }
        if (has_node) {   // keep packed mu for the B8 PBC write
#pragma unroll
            for (int k = 0; k < 8; k++) pm01[k] = pack_bf2(m[0][k], m[1][k]);
#pragma unroll
            for (int p = 0; p < 4; p++)
                pm2p[p] = bf16_rtne(m[2][2 * p]) | (bf16_rtne(m[2][2 * p + 1]) << 16);
        }
    }
    __syncthreads();                                              // B6

    if (has_node) {
        unsigned short* Ah = Wsp;   // reuse (Wsp reads finished at B6)
        bf16x8 a1[4];
#pragma unroll
        for (int ks = 0; ks < 4; ks++)
            a1[ks] = *(const bf16x8*)&A[c0 * 264 + ks * 32 + quad * 8];
        {
            float bb = nib1[16 * w + c0];
            f32x4 acc = (f32x4){bb, bb, bb, bb};
#pragma unroll
            for (int ks = 0; ks < 4; ks++) {
                bf16x8 b = *(const bf16x8*)&niW1t[(16 * w + c0) * 128 + ks * 32 + quad * 8];
                acc = __builtin_amdgcn_mfma_f32_16x16x32_bf16(a1[ks], b, acc, 0, 0, 0);
            }
#pragma unroll
            for (int r = 0; r < 4; r++) {
                float aa = acc[r];
                Ah[(quad * 4 + r) * 136 + 16 * w + c0] =
                    (unsigned short)bf16_rtne(aa / (1.f + __expf(-aa)));
            }
        }
        __syncthreads();                                          // B7

        bf16x8 a4[4];
#pragma unroll
        for (int ks = 0; ks < 4; ks++)
            a4[ks] = *(const bf16x8*)&Ah[c0 * 136 + ks * 32 + quad * 8];
#pragma unroll
        for (int jj = 0; jj < 3; jj++) {
            int jx = 3 * w + jj;
            float bb = nib2[16 * jx + c0];
            f32x4 acc = (f32x4){bb, bb, bb, bb};
#pragma unroll
            for (int ks = 0; ks < 4; ks++) {
                bf16x8 b = *(const bf16x8*)&niW2t[(16 * jx + c0) * 128 + ks * 32 + quad * 8];
                acc = __builtin_amdgcn_mfma_f32_16x16x32_bf16(a4[ks], b, acc, 0, 0, 0);
            }
#pragma unroll
            for (int r = 0; r < 4; r++)
                Xs[(quad * 4 + r) * XS + 16 * jx + c0] = acc[r];
        }
        __syncthreads();                                          // B8

        if (t < 256 && gn < N) {
            unsigned int d[8];
#pragma unroll
            for (int k = 0; k < 8; k++) {
                float x0 = Xs[n * XS + fi + k];
                float x1 = Xs[n * XS + 128 + fi + k];
                d[k] = pack_bf2(x0, x1);
            }
            size_t ba = (size_t)gn * 128 + fi;
            *(uint4*)&PA[ba]     = make_uint4(d[0], d[1], d[2], d[3]);
            *(uint4*)&PA[ba + 4] = make_uint4(d[4], d[5], d[6], d[7]);

            size_t bb2 = (size_t)gn * 256 + 2 * fi;
#pragma unroll
            for (int p = 0; p < 4; p++) {
                int k0 = 2 * p, k1 = 2 * p + 1;
                float x2a = Xs[n * XS + 256 + fi + k0];
                float x2b = Xs[n * XS + 256 + fi + k1];
                unsigned int c0w = bf16_rtne(x2a) | (pm2p[p] << 16);           // (xm|mu2)
                unsigned int c1w = bf16_rtne(x2b) | (pm2p[p] & 0xffff0000u);   // (xm|mu2)
                *(uint4*)&PBC[bb2 + 4 * p] =
                    make_uint4(pm01[k0], c0w, pm01[k1], c1w);
            }
        }
    }
}

// ---------------------------------------------------------------------------
extern "C" void kernel_launch(void* const* d_in, const int* in_sizes, int n_in,
                              void* d_out, int out_size, void* d_ws, size_t ws_size,
                              hipStream_t stream) {
    const int*   Z      = (const int*)d_in[0];
    const float* r_ij   = (const float*)d_in[1];
    const int*   idx_i  = (const int*)d_in[2];
    const int*   idx_j  = (const int*)d_in[3];
    const float* emb    = (const float*)d_in[4];
    const float* filt_W = (const float*)d_in[5];
    const float* filt_b = (const float*)d_in[6];
    const float* int_W1 = (const float*)d_in[7];
    const float* int_b1 = (const float*)d_in[8];
    const float* int_W2 = (const float*)d_in[9];
    const float* int_b2 = (const float*)d_in[10];
    const float* mix_W1 = (const float*)d_in[11];
    const float* mix_b1 = (const float*)d_in[12];
    const float* mix_W2 = (const float*)d_in[13];
    const float* mix_b2 = (const float*)d_in[14];
    const float* mux_W  = (const float*)d_in[15];

    int N = in_sizes[0];
    int E = in_sizes[2];

    float* q   = (float*)d_out;              // [N,128]  q state (fp32)
    float* muD = q + (size_t)N * 128;        // [N,3,128] mu state (fp32)

    unsigned int* geom = (unsigned int*)d_ws;                 // E*16 u32 (64 B/edge)
    unsigned int* P = geom + (size_t)E * 16;                  // N*384 u32 (PA + PBC)
    int* row_ptr = (int*)(P + (size_t)N * 384);               // N+1
    uintptr_t waddr = (uintptr_t)(row_ptr + N + 1);
    waddr = (waddr + 15) & ~(uintptr_t)15;
    unsigned short* muxWt = (unsigned short*)waddr;   // 3*256*128
    unsigned short* W1t   = muxWt + 98304;            // 3*128*256
    unsigned short* W2t   = W1t + 98304;              // 3*384*128
    unsigned short* iW1t  = W2t + 147456;             // 3*128*128
    unsigned short* iW2t  = iW1t + 49152;             // 3*384*128
    unsigned short* filtWt = iW2t + 147456;           // 3*384*24 f16

    int nbR = (N + 1 + 255) / 256;
    int nbG = (E + 255) / 256;
    k_pre<<<nbR + nbG + 2220, 256, 0, stream>>>(
        idx_i, row_ptr, r_ij, geom,
        mux_W, mix_W1, mix_W2, int_W1, int_W2, filt_W, filt_b,
        muxWt, W1t, W2t, iW1t, iW2t, filtWt, N, E, nbR, nbG);

    int tiles = (N + 15) / 16;
    k_node_mfma<<<tiles, 256, 0, stream>>>(
        Z, emb, q, iW1t, int_b1, iW2t, int_b2, P, N);
    for (int l = 0; l < 3; l++) {
        if (l == 0)
            k_edge<false><<<(N + NPB - 1) / NPB, 256, 0, stream>>>(
                P, geom, idx_j, row_ptr, filtWt, q, muD, N, E);
        else
            k_edge<true><<<(N + NPB - 1) / NPB, 256, 0, stream>>>(
                P, geom, idx_j, row_ptr, filtWt + (size_t)l * 9216, q, muD, N, E);
        int nl = (l < 2) ? (l + 1) : 0;
        k_mix_fused<<<tiles, 512, 0, stream>>>(
            q, muD, muxWt + (size_t)l * 32768, W1t + (size_t)l * 32768,
            W2t + (size_t)l * 49152, mix_b1 + l * 128, mix_b2 + l * 384,
            iW1t + (size_t)nl * 16384, int_b1 + nl * 128,
            iW2t + (size_t)nl * 49152, int_b2 + nl * 384,
            (l < 2) ? 1 : 0, P, N);
    }
    // q in d_out; final mu (fp32 state) in muD = d_out mu region.
}